// Round 1
// baseline (1248.103 us; speedup 1.0000x reference)
//
#include <hip/hip_runtime.h>
#include <cstdint>

#define THRESH 0.8f
#define RR2    2.25f
#define KMAX   4096      // unified kept cap
#define KSEG   2048      // per-segment kept cap (LDS-resident in greedy)
#define ALDS   2048      // kept staged in LDS for assign
#define NB     4096      // beta buckets per segment
#define NSEG_MAX 4
#define NBTOT  (NB * NSEG_MAX)

// counters (ints): [0]=keptCnt [1]=cntUnassigned [2]=G [3]=hasUn [8]=U (candidate count)
#define C_KEPT  0
#define C_UN    1
#define C_G     2
#define C_HASUN 3
#define C_U0    8

// f32, no FMA contraction, left-assoc: matches numpy/XLA (x*x + y*y) + z*z
__device__ __forceinline__ float dist2(const float4 a, const float4 b) {
#pragma clang fp contract(off)
  float dx = a.x - b.x;
  float dy = a.y - b.y;
  float dz = a.z - b.z;
  return dx * dx + dy * dy + dz * dz;
}

__global__ void k_init(int* counters, int* cntKept, int* groupCount,
                       int* bucketCnt, int* bucketFill) {
  int i = blockIdx.x * blockDim.x + threadIdx.x;
  if (i < 64) counters[i] = 0;
  if (i < KMAX) cntKept[i] = 0;
  if (i < KMAX + 2) groupCount[i] = 0;
  if (i < NBTOT) { bucketCnt[i] = 0; bucketFill[i] = 0; }
}

__device__ __forceinline__ int beta_bucket(float b) {
  int t = (int)((b - 0.8f) * 20480.0f);   // [0.8,1) -> [0,4096)
  return t < 0 ? 0 : (t > NB - 1 ? NB - 1 : t);
}

// ord-bucket = seg*NB + (NB-1 - beta_bucket): ascending ord == segment-major, beta-desc
__global__ void k_compact(const float* __restrict__ betas, const float* __restrict__ cc,
                          const int* __restrict__ rs, int nrs, int N,
                          float4* __restrict__ ucand, int* __restrict__ uidx,
                          int* __restrict__ ubkt, int* bucketCnt, int* mCnt) {
  int i = blockIdx.x * blockDim.x + threadIdx.x;
  if (i >= N) return;
  float b = betas[i];
  if (b >= THRESH) {
    int slot = atomicAdd(mCnt, 1);
    ucand[slot] = make_float4(cc[3 * i], cc[3 * i + 1], cc[3 * i + 2], b);
    uidx[slot] = i;
    int s = 0;
    for (int t = 1; t < nrs - 1; ++t) s += (i >= rs[t]) ? 1 : 0;
    int ord = s * NB + (NB - 1 - beta_bucket(b));
    ubkt[slot] = ord;
    atomicAdd(&bucketCnt[ord], 1);
  }
}

// ascending prefix sum over NBTOT ord-buckets; bucketStart[NBTOT] = total
__global__ void k_bucketscan(const int* __restrict__ bucketCnt, int* __restrict__ bucketStart) {
  __shared__ int partial[256];
  int t = threadIdx.x;
  const int PER = NBTOT / 256;   // 64
  int sum = 0;
  for (int q = 0; q < PER; ++q) sum += bucketCnt[t * PER + q];
  partial[t] = sum;
  __syncthreads();
  if (t == 0) {
    int acc = 0;
    for (int i = 0; i < 256; ++i) { int v = partial[i]; partial[i] = acc; acc += v; }
    bucketStart[NBTOT] = acc;
  }
  __syncthreads();
  int acc = partial[t];
  for (int q = 0; q < PER; ++q) {
    int b = t * PER + q;
    bucketStart[b] = acc;
    acc += bucketCnt[b];
  }
}

__global__ void k_bucketscatter(const int* __restrict__ counters,
                                const float4* __restrict__ ucand, const int* __restrict__ uidx,
                                const int* __restrict__ ubkt,
                                const int* __restrict__ bucketStart, int* bucketFill,
                                float4* __restrict__ scand, int* __restrict__ sidx) {
  int i = blockIdx.x * blockDim.x + threadIdx.x;
  if (i >= counters[C_U0]) return;
  int b = ubkt[i];
  int pos = bucketStart[b] + atomicAdd(&bucketFill[b], 1);
  scand[pos] = ucand[i];
  sidx[pos] = uidx[i];
}

// one thread per ord-bucket: insertion sort by (beta desc, idx asc) -> exact per-segment order
__global__ void k_bucketsort(const int* __restrict__ bucketCnt, const int* __restrict__ bucketStart,
                             float4* __restrict__ scand, int* __restrict__ sidx) {
  int b = blockIdx.x * blockDim.x + threadIdx.x;
  if (b >= NBTOT) return;
  int start = bucketStart[b];
  int end = start + bucketCnt[b];
  for (int a = start + 1; a < end; ++a) {
    float4 v = scand[a]; int vi = sidx[a];
    int p = a - 1;
    while (p >= start && (scand[p].w < v.w || (scand[p].w == v.w && sidx[p] > vi))) {
      scand[p + 1] = scand[p]; sidx[p + 1] = sidx[p];
      --p;
    }
    scand[p + 1] = v; sidx[p + 1] = vi;
  }
}

// Exact greedy, SINGLE WAVE per segment.
// Rationale (rocprof r0): WRITE_SIZE=2.3KB => only ~118 kept total (~59/seg),
// so the old 16-wave kill-split + 2x 1024-thread barriers per 64-cand chunk was
// pure coordination overhead (417us @ VALUBusy 0.32%). One wave, 128 cands/chunk
// (2/lane), zero barriers (all-lane same-address LDS write => same-thread
// write->read ordering), prefetched next-chunk loads (no barrier => no vmcnt(0)
// drain), wave-uniform early-exit kill loop.
__global__ void __launch_bounds__(64) k_greedy(
    const float4* __restrict__ scand, const int* __restrict__ sidx,
    const int* __restrict__ bucketStart,
    float4* __restrict__ segKeptCand, int* __restrict__ segKeptIdx,
    int* __restrict__ keptCntSeg) {
  __shared__ float4 kc[KSEG];                  // 32 KiB
  int s = blockIdx.x;
  int base = bucketStart[s * NB];
  int U = bucketStart[(s + 1) * NB] - base;
  int lane = threadIdx.x;                      // 0..63 (one wave)
  int K = 0;

  if (U > 0) {
    // prefetch chunk 0
    int tA = lane, tB = lane + 64;
    float4 cA = scand[base + (tA < U ? tA : 0)];
    float4 cB = scand[base + (tB < U ? tB : 0)];
    int    pA = sidx[base + (tA < U ? tA : 0)];
    int    pB = sidx[base + (tB < U ? tB : 0)];

    for (int c0 = 0; c0 < U; c0 += 128) {
      bool validA = (c0 + lane) < U;
      bool validB = (c0 + 64 + lane) < U;
      float4 a = cA, b = cB;
      int ia = pA, ib = pB;

      // prefetch next chunk: loads stay in flight across the whole body
      int nA = c0 + 128 + lane, nB = nA + 64;
      cA = scand[base + (nA < U ? nA : 0)];
      cB = scand[base + (nB < U ? nB : 0)];
      pA = sidx[base + (nA < U ? nA : 0)];
      pB = sidx[base + (nB < U ? nB : 0)];

      // kill vs existing kept (LDS broadcast reads, uniform early-exit per 8)
      bool aliveA = validA, aliveB = validB;
      int Kc = K < KSEG ? K : KSEG;
      int j = 0;
      int Kc8 = Kc & ~7;
      for (; j < Kc8; j += 8) {
#pragma unroll
        for (int q = 0; q < 8; ++q) {
          float4 k0 = kc[j + q];
          aliveA = aliveA && (dist2(k0, a) > RR2);
          aliveB = aliveB && (dist2(k0, b) > RR2);
        }
        if (!__any(aliveA | aliveB)) break;
      }
      if (__any(aliveA | aliveB))
        for (; j < Kc; ++j) {
          float4 k0 = kc[j];
          aliveA = aliveA && (dist2(k0, a) > RR2);
          aliveB = aliveB && (dist2(k0, b) > RR2);
        }

      // resolve A-half (positions c0..c0+63, ascending lane = sorted order)
      unsigned long long am = __ballot(aliveA);
      while (am) {
        int i = __ffsll((long long)am) - 1;
        float4 kf = make_float4(__shfl(a.x, i), __shfl(a.y, i),
                                __shfl(a.z, i), __shfl(a.w, i));
        int ii = __shfl(ia, i);
        if (K < KSEG) {
          kc[K] = kf;                           // all lanes, same addr+value
          if (lane == 0) {
            segKeptCand[s * KSEG + K] = kf;
            segKeptIdx[s * KSEG + K] = ii;
          }
        }
        ++K;
        if (aliveA && lane > i && dist2(kf, a) <= RR2) aliveA = false;
        if (aliveB && dist2(kf, b) <= RR2) aliveB = false;  // all B are later
        am = __ballot(aliveA);
        am &= ~((i < 63) ? ((1ull << (i + 1)) - 1ull) : ~0ull);
      }

      // resolve B-half (positions c0+64..c0+127)
      unsigned long long bm = __ballot(aliveB);
      while (bm) {
        int i = __ffsll((long long)bm) - 1;
        float4 kf = make_float4(__shfl(b.x, i), __shfl(b.y, i),
                                __shfl(b.z, i), __shfl(b.w, i));
        int ii = __shfl(ib, i);
        if (K < KSEG) {
          kc[K] = kf;
          if (lane == 0) {
            segKeptCand[s * KSEG + K] = kf;
            segKeptIdx[s * KSEG + K] = ii;
          }
        }
        ++K;
        if (aliveB && lane > i && dist2(kf, b) <= RR2) aliveB = false;
        bm = __ballot(aliveB);
        bm &= ~((i < 63) ? ((1ull << (i + 1)) - 1ull) : ~0ull);
      }
    }
  }
  if (lane == 0) keptCntSeg[s] = (K < KSEG) ? K : KSEG;
}

// unify per-segment kept lists (segment-major; order within segment = greedy order)
__global__ void k_merge(int nseg, const float4* __restrict__ segKeptCand,
                        const int* __restrict__ segKeptIdx, const int* __restrict__ keptCntSeg,
                        float4* __restrict__ keptCand, int* __restrict__ keptIdx,
                        int* __restrict__ segKeptStart, int* __restrict__ segKeptCnt,
                        int* counters) {
  __shared__ int pre[NSEG_MAX + 1];
  if (threadIdx.x == 0) {
    int acc = 0;
    for (int s2 = 0; s2 < nseg; ++s2) {
      pre[s2] = acc;
      int cn = keptCntSeg[s2]; if (cn > KSEG) cn = KSEG;
      acc += cn;
    }
    pre[nseg] = acc;
    counters[C_KEPT] = (acc < KMAX) ? acc : KMAX;
  }
  __syncthreads();
  for (int s2 = 0; s2 < nseg; ++s2) {
    int cn = keptCntSeg[s2]; if (cn > KSEG) cn = KSEG;
    if (threadIdx.x == 0) { segKeptStart[s2] = pre[s2]; segKeptCnt[s2] = cn; }
    for (int j = threadIdx.x; j < cn; j += blockDim.x) {
      keptCand[pre[s2] + j] = segKeptCand[s2 * KSEG + j];
      keptIdx[pre[s2] + j] = segKeptIdx[s2 * KSEG + j];
    }
  }
}

// Each point -> FIRST kept (greedy order, own segment) within radius.
// Kept list + idx staged in LDS; x4-unrolled early-exit scan (wave-uniform j -> LDS broadcast);
// per-block LDS histogram -> one coalesced flush (no hot global atomics).
__global__ void __launch_bounds__(256) k_assign(
    const float* __restrict__ cc, const int* __restrict__ rs, int nrs, int N,
    const float4* __restrict__ keptCand, const int* __restrict__ keptIdx,
    const int* __restrict__ segKeptStart, const int* __restrict__ segKeptCnt,
    const int* __restrict__ counters,
    int* cntKept, int* countersW, int* __restrict__ assoInt,
    int* __restrict__ keptPos) {
  __shared__ float4 sk[ALDS];     // 32 KiB
  __shared__ int    sIx[ALDS];    // 8 KiB
  __shared__ int    shist[ALDS];  // 8 KiB
  __shared__ int    sUn;
  int Ktot = counters[C_KEPT];
  if (Ktot > KMAX) Ktot = KMAX;
  int Kl = Ktot < ALDS ? Ktot : ALDS;
  for (int j = threadIdx.x; j < Kl; j += blockDim.x) {
    sk[j] = keptCand[j];
    sIx[j] = keptIdx[j];
    shist[j] = 0;
  }
  if (threadIdx.x == 0) sUn = 0;
  __syncthreads();

  int i = blockIdx.x * blockDim.x + threadIdx.x;
  int bpos = -1, bidx = -1;
  bool active = i < N;
  if (active) {
    float4 p = make_float4(cc[3 * i], cc[3 * i + 1], cc[3 * i + 2], 0.f);
    int seg = 0;
    for (int t = 1; t < nrs - 1; ++t) seg += (i >= rs[t]) ? 1 : 0;
    int ks = segKeptStart[seg];
    int end = ks + segKeptCnt[seg];
    int lim = end < Kl ? end : Kl;
    int j = ks;
    for (; j + 3 < lim; j += 4) {     // 4 LDS reads per waitcnt -> 4x shorter chain
      bool h0 = dist2(sk[j], p) <= RR2;
      bool h1 = dist2(sk[j + 1], p) <= RR2;
      bool h2 = dist2(sk[j + 2], p) <= RR2;
      bool h3 = dist2(sk[j + 3], p) <= RR2;
      if (h0 | h1 | h2 | h3) { bpos = h0 ? j : h1 ? j + 1 : h2 ? j + 2 : j + 3; break; }
    }
    if (bpos < 0)
      for (; j < lim; ++j)
        if (dist2(sk[j], p) <= RR2) { bpos = j; break; }
    if (bpos < 0)                      // overflow tail beyond LDS (Ktot>ALDS): global
      for (; j < end; ++j)
        if (dist2(keptCand[j], p) <= RR2) { bpos = j; break; }
    if (bpos >= 0) {
      bidx = (bpos < Kl) ? sIx[bpos] : keptIdx[bpos];
      assoInt[i] = bidx;
      keptPos[i] = bpos;
      if (bpos < Kl) atomicAdd(&shist[bpos], 1);
      else atomicAdd(&cntKept[bpos], 1);
    } else {
      assoInt[i] = -1;
      keptPos[i] = -1;
      atomicAdd(&sUn, 1);
    }
  }
  __syncthreads();
  for (int j = threadIdx.x; j < Kl; j += blockDim.x) {
    int h = shist[j];
    if (h) atomicAdd(&cntKept[j], h);  // distinct addresses across lanes: parallel at L2
  }
  if (threadIdx.x == 0 && sUn) atomicAdd(&countersW[C_UN], sUn);
}

// rank kept by original index (asso values ascending); group 0 = unassigned if present
__global__ void k_rank(const int* __restrict__ keptIdx, int* counters,
                       const int* __restrict__ cntKept,
                       int* __restrict__ rankOfKept, int* __restrict__ groupCount) {
  __shared__ int sIdx[KMAX];   // 16 KiB
  int K = counters[C_KEPT];
  if (K > KMAX) K = KMAX;
  for (int j = threadIdx.x; j < K; j += blockDim.x) sIdx[j] = keptIdx[j];
  __syncthreads();
  int un = counters[C_UN];
  int hasUn = un > 0 ? 1 : 0;
  int gid = blockIdx.x * blockDim.x + threadIdx.x;
  int stride = gridDim.x * blockDim.x;
  if (gid == 0) {
    counters[C_HASUN] = hasUn;
    counters[C_G] = K + hasUn;
    if (hasUn) groupCount[0] = un;
  }
  for (int j = gid; j < K; j += stride) {
    int myIdx = sIdx[j];
    int r = hasUn;
    for (int j2 = 0; j2 < K; ++j2)
      r += (sIdx[j2] < myIdx) ? 1 : 0;
    rankOfKept[j] = r;
    groupCount[r] = cntKept[j];
  }
}

__global__ void k_pointrank(int N, const int* __restrict__ keptPos,
                            const int* __restrict__ rankOfKept,
                            const int* __restrict__ assoInt,
                            int* __restrict__ pointRank, float* __restrict__ outAsso) {
  int i = blockIdx.x * blockDim.x + threadIdx.x;
  if (i >= N) return;
  int p = keptPos[i];
  pointRank[i] = (p < 0) ? 0 : rankOfKept[p];
  outAsso[i] = (float)assoInt[i];
}

// parallel exclusive prefix over groupCount[0..G) (single block, 256 threads)
__global__ void k_scan(const int* __restrict__ counters, const int* __restrict__ groupCount,
                       int* __restrict__ starts) {
  __shared__ int partial[256];
  int G = counters[C_G];
  int t = threadIdx.x;
  const int PER = (KMAX + 2 + 255) / 256;
  int sum = 0;
  for (int q = 0; q < PER; ++q) {
    int idx = t * PER + q;
    if (idx < G) sum += groupCount[idx];
  }
  partial[t] = sum;
  __syncthreads();
  if (t == 0) {
    int acc = 0;
    for (int i = 0; i < 256; ++i) { int v = partial[i]; partial[i] = acc; acc += v; }
  }
  __syncthreads();
  int acc = partial[t];
  for (int q = 0; q < PER; ++q) {
    int idx = t * PER + q;
    if (idx < G) { starts[idx] = acc; acc += groupCount[idx]; }
  }
}

__global__ void k_psrs(int N, const int* __restrict__ counters, const int* __restrict__ starts,
                       float* __restrict__ outPsrs) {
  int p = blockIdx.x * blockDim.x + threadIdx.x;
  if (p > N) return;
  int G = counters[C_G];
  outPsrs[p] = (p < G) ? (float)starts[p] : (float)N;
}

// stable counting-sort scatter: one block per group, ballot prefix within chunks
__global__ void k_scatter(int N, const int* __restrict__ counters,
                          const int* __restrict__ pointRank, const int* __restrict__ starts,
                          int* __restrict__ order, float* __restrict__ outSids,
                          float* __restrict__ outBelongs) {
  int g = blockIdx.x;
  if (g >= counters[C_G]) return;
  int base = starts[g];
  __shared__ int wsum[4];
  int lane = threadIdx.x & 63, wv = threadIdx.x >> 6;
  for (int i0 = 0; i0 < N; i0 += 256) {
    int i = i0 + threadIdx.x;
    bool m = (i < N) && (pointRank[i] == g);
    unsigned long long bal = __ballot(m);
    int pw = __popcll(bal & ((1ull << lane) - 1ull));
    if (lane == 0) wsum[wv] = __popcll(bal);
    __syncthreads();
    int off = 0;
    for (int q = 0; q < wv; ++q) off += wsum[q];
    int tot = wsum[0] + wsum[1] + wsum[2] + wsum[3];
    if (m) {
      int pos = base + off + pw;
      order[pos] = i;
      outSids[pos] = (float)i;
      outBelongs[pos] = (float)g;
    }
    base += tot;
    __syncthreads();
  }
}

// flat grid-stride float4 row gather (F % 4 == 0 path)
__global__ void k_gather4(const float4* __restrict__ data4, const int* __restrict__ order,
                          int F4, int total4, float4* __restrict__ out4) {
  int stride = gridDim.x * blockDim.x;
  for (int idx = blockIdx.x * blockDim.x + threadIdx.x; idx < total4; idx += stride) {
    int row = idx / F4;
    int col = idx - row * F4;
    out4[idx] = data4[(size_t)order[row] * F4 + col];
  }
}

__global__ void k_gather(const float* __restrict__ data, const int* __restrict__ order,
                         int F, float* __restrict__ out) {
  int row = blockIdx.x;
  int src = order[row];
  for (int f = threadIdx.x; f < F; f += blockDim.x)
    out[(size_t)row * F + f] = data[(size_t)src * F + f];
}

extern "C" void kernel_launch(void* const* d_in, const int* in_sizes, int n_in,
                              void* d_out, int out_size, void* d_ws, size_t ws_size,
                              hipStream_t stream) {
  const float* data  = (const float*)d_in[0];
  const float* cc    = (const float*)d_in[1];
  const float* betas = (const float*)d_in[2];
  const int*   rs    = (const int*)d_in[3];
  int nrs = in_sizes[3];
  int N   = in_sizes[2];           // betas is (N,1)
  int F   = in_sizes[0] / N;       // 128
  int nseg = nrs - 1; if (nseg < 1) nseg = 1; if (nseg > NSEG_MAX) nseg = NSEG_MAX;

  float* out = (float*)d_out;
  float* outSdata   = out;
  float* outPsrs    = outSdata + (size_t)N * F;
  float* outSids    = outPsrs + (N + 1);
  float* outAsso    = outSids + N;
  float* outBelongs = outAsso + N;

  char* p = (char*)d_ws;
  auto alloc = [&](size_t bytes) { void* r = (void*)p; p += (bytes + 255) & ~(size_t)255; return r; };
  int*    counters     = (int*)alloc(64 * 4);
  float4* ucand        = (float4*)alloc((size_t)N * 16);
  int*    uidx         = (int*)alloc((size_t)N * 4);
  int*    ubkt         = (int*)alloc((size_t)N * 4);
  float4* scand        = (float4*)alloc((size_t)N * 16);
  int*    sidx         = (int*)alloc((size_t)N * 4);
  int*    bucketCnt    = (int*)alloc(NBTOT * 4);
  int*    bucketStart  = (int*)alloc((NBTOT + 1) * 4);
  int*    bucketFill   = (int*)alloc(NBTOT * 4);
  float4* segKeptCand  = (float4*)alloc((size_t)NSEG_MAX * KSEG * 16);
  int*    segKeptIdx   = (int*)alloc((size_t)NSEG_MAX * KSEG * 4);
  int*    keptCntSeg   = (int*)alloc(NSEG_MAX * 4);
  int*    segKeptStart = (int*)alloc(NSEG_MAX * 4);
  int*    segKeptCnt   = (int*)alloc(NSEG_MAX * 4);
  float4* keptCand     = (float4*)alloc(KMAX * 16);
  int*    keptIdx      = (int*)alloc(KMAX * 4);
  int*    rankOfKept   = (int*)alloc(KMAX * 4);
  int*    cntKept      = (int*)alloc(KMAX * 4);
  int*    groupCount   = (int*)alloc((KMAX + 2) * 4);
  int*    starts       = (int*)alloc((KMAX + 2) * 4);
  int*    assoInt      = (int*)alloc((size_t)N * 4);
  int*    keptPos      = (int*)alloc((size_t)N * 4);
  int*    pointRank    = (int*)alloc((size_t)N * 4);
  int*    order        = (int*)alloc((size_t)N * 4);

  int nb = (N + 255) / 256;

  k_init<<<(NBTOT + 255) / 256, 256, 0, stream>>>(counters, cntKept, groupCount,
                                                  bucketCnt, bucketFill);

  k_compact<<<nb, 256, 0, stream>>>(betas, cc, rs, nrs, N, ucand, uidx, ubkt,
                                    bucketCnt, &counters[C_U0]);

  k_bucketscan<<<1, 256, 0, stream>>>(bucketCnt, bucketStart);

  k_bucketscatter<<<nb, 256, 0, stream>>>(counters, ucand, uidx, ubkt,
                                          bucketStart, bucketFill, scand, sidx);

  k_bucketsort<<<NBTOT / 256, 256, 0, stream>>>(bucketCnt, bucketStart, scand, sidx);

  k_greedy<<<nseg, 64, 0, stream>>>(scand, sidx, bucketStart,
                                    segKeptCand, segKeptIdx, keptCntSeg);

  k_merge<<<1, 256, 0, stream>>>(nseg, segKeptCand, segKeptIdx, keptCntSeg,
                                 keptCand, keptIdx, segKeptStart, segKeptCnt, counters);

  k_assign<<<nb, 256, 0, stream>>>(cc, rs, nrs, N, keptCand, keptIdx,
                                   segKeptStart, segKeptCnt, counters, cntKept, counters,
                                   assoInt, keptPos);

  k_rank<<<32, 256, 0, stream>>>(keptIdx, counters, cntKept, rankOfKept, groupCount);

  k_pointrank<<<nb, 256, 0, stream>>>(N, keptPos, rankOfKept, assoInt, pointRank, outAsso);

  k_scan<<<1, 256, 0, stream>>>(counters, groupCount, starts);

  k_psrs<<<(N + 256) / 256, 256, 0, stream>>>(N, counters, starts, outPsrs);

  k_scatter<<<KMAX + 1, 256, 0, stream>>>(N, counters, pointRank, starts, order,
                                          outSids, outBelongs);

  if (F % 4 == 0) {
    int F4 = F / 4;
    int total4 = N * F4;
    k_gather4<<<2048, 256, 0, stream>>>((const float4*)data, order, F4, total4,
                                        (float4*)outSdata);
  } else {
    k_gather<<<N, 128, 0, stream>>>(data, order, F, outSdata);
  }
}

// Round 3
// 1037.617 us; speedup vs baseline: 1.2029x; 1.2029x over previous
//
#include <hip/hip_runtime.h>
#include <cstdint>

#define THRESH 0.8f
#define RR2    2.25f
#define KMAX   4096      // unified kept cap
#define KSEG   2048      // per-segment kept cap (LDS-resident in greedy)
#define ALDS   2048      // kept staged in LDS for assign
#define NB     4096      // beta buckets per segment
#define NSEG_MAX 4
#define NBTOT  (NB * NSEG_MAX)

#define GW     4         // greedy waves per block (R0 had 16; K~59 kept needs far fewer)

// counters (ints): [0]=keptCnt [1]=cntUnassigned [2]=G [3]=hasUn [8]=U (candidate count)
#define C_KEPT  0
#define C_UN    1
#define C_G     2
#define C_HASUN 3
#define C_U0    8

// f32, no FMA contraction, left-assoc: matches numpy/XLA (x*x + y*y) + z*z
__device__ __forceinline__ float dist2(const float4 a, const float4 b) {
#pragma clang fp contract(off)
  float dx = a.x - b.x;
  float dy = a.y - b.y;
  float dz = a.z - b.z;
  return dx * dx + dy * dy + dz * dz;
}

__global__ void k_init(int* counters, int* cntKept, int* groupCount,
                       int* bucketCnt, int* bucketFill) {
  int i = blockIdx.x * blockDim.x + threadIdx.x;
  if (i < 64) counters[i] = 0;
  if (i < KMAX) cntKept[i] = 0;
  if (i < KMAX + 2) groupCount[i] = 0;
  if (i < NBTOT) { bucketCnt[i] = 0; bucketFill[i] = 0; }
}

__device__ __forceinline__ int beta_bucket(float b) {
  int t = (int)((b - 0.8f) * 20480.0f);   // [0.8,1) -> [0,4096)
  return t < 0 ? 0 : (t > NB - 1 ? NB - 1 : t);
}

// ord-bucket = seg*NB + (NB-1 - beta_bucket): ascending ord == segment-major, beta-desc
__global__ void k_compact(const float* __restrict__ betas, const float* __restrict__ cc,
                          const int* __restrict__ rs, int nrs, int N,
                          float4* __restrict__ ucand, int* __restrict__ uidx,
                          int* __restrict__ ubkt, int* bucketCnt, int* mCnt) {
  int i = blockIdx.x * blockDim.x + threadIdx.x;
  if (i >= N) return;
  float b = betas[i];
  if (b >= THRESH) {
    int slot = atomicAdd(mCnt, 1);
    ucand[slot] = make_float4(cc[3 * i], cc[3 * i + 1], cc[3 * i + 2], b);
    uidx[slot] = i;
    int s = 0;
    for (int t = 1; t < nrs - 1; ++t) s += (i >= rs[t]) ? 1 : 0;
    int ord = s * NB + (NB - 1 - beta_bucket(b));
    ubkt[slot] = ord;
    atomicAdd(&bucketCnt[ord], 1);
  }
}

// ascending prefix sum over NBTOT ord-buckets; bucketStart[NBTOT] = total
__global__ void k_bucketscan(const int* __restrict__ bucketCnt, int* __restrict__ bucketStart) {
  __shared__ int partial[256];
  int t = threadIdx.x;
  const int PER = NBTOT / 256;   // 64
  int sum = 0;
  for (int q = 0; q < PER; ++q) sum += bucketCnt[t * PER + q];
  partial[t] = sum;
  __syncthreads();
  if (t == 0) {
    int acc = 0;
    for (int i = 0; i < 256; ++i) { int v = partial[i]; partial[i] = acc; acc += v; }
    bucketStart[NBTOT] = acc;
  }
  __syncthreads();
  int acc = partial[t];
  for (int q = 0; q < PER; ++q) {
    int b = t * PER + q;
    bucketStart[b] = acc;
    acc += bucketCnt[b];
  }
}

__global__ void k_bucketscatter(const int* __restrict__ counters,
                                const float4* __restrict__ ucand, const int* __restrict__ uidx,
                                const int* __restrict__ ubkt,
                                const int* __restrict__ bucketStart, int* bucketFill,
                                float4* __restrict__ scand, int* __restrict__ sidx) {
  int i = blockIdx.x * blockDim.x + threadIdx.x;
  if (i >= counters[C_U0]) return;
  int b = ubkt[i];
  int pos = bucketStart[b] + atomicAdd(&bucketFill[b], 1);
  scand[pos] = ucand[i];
  sidx[pos] = uidx[i];
}

// one thread per ord-bucket: insertion sort by (beta desc, idx asc) -> exact per-segment order
__global__ void k_bucketsort(const int* __restrict__ bucketCnt, const int* __restrict__ bucketStart,
                             float4* __restrict__ scand, int* __restrict__ sidx) {
  int b = blockIdx.x * blockDim.x + threadIdx.x;
  if (b >= NBTOT) return;
  int start = bucketStart[b];
  int end = start + bucketCnt[b];
  for (int a = start + 1; a < end; ++a) {
    float4 v = scand[a]; int vi = sidx[a];
    int p = a - 1;
    while (p >= start && (scand[p].w < v.w || (scand[p].w == v.w && sidx[p] > vi))) {
      scand[p + 1] = scand[p]; sidx[p + 1] = sidx[p];
      --p;
    }
    scand[p + 1] = v; sidx[p + 1] = vi;
  }
}

// Cooperative exact greedy — R0 structure (known-good) with two minimal diffs:
//  (a) GW=4 waves / 256 threads instead of 16/1024: kill-split of K~59 kept over
//      4 waves (~15 each) is ample; barriers are 4-wave not 16-wave.
//  (b) register double-buffer prefetch of the next 64-candidate chunk: removes
//      the ~900cy cold global-load latency from the per-chunk critical path
//      (R0 loaded the chunk on demand, serially, every chunk).
// Resolve logic (shuffle-broadcast, wave 0, lane-0 kc write) is VERBATIM R0.
__global__ void __launch_bounds__(256) k_greedy(
    const float4* __restrict__ scand, const int* __restrict__ sidx,
    const int* __restrict__ bucketStart,
    float4* __restrict__ segKeptCand, int* __restrict__ segKeptIdx,
    int* __restrict__ keptCntSeg) {
  __shared__ float4 kc[KSEG];                  // 32 KiB
  __shared__ unsigned long long killM[GW];
  __shared__ int sK;
  int s = blockIdx.x;
  int base = bucketStart[s * NB];
  int U = bucketStart[(s + 1) * NB] - base;
  int lane = threadIdx.x & 63, w = threadIdx.x >> 6;
  if (threadIdx.x == 0) sK = 0;
  __syncthreads();

  // per-wave private prefetch of chunk 0 (each wave holds its own copy)
  int t0 = lane;
  float4 cNext = scand[base + (t0 < U ? t0 : 0)];
  int    iNext = sidx[base + (t0 < U ? t0 : 0)];

  for (int c0 = 0; c0 < U; c0 += 64) {
    int t = c0 + lane;
    bool valid = t < U;
    float4 c = cNext;
    int cidx = iNext;

    // prefetch next chunk (in flight across kill + resolve + barriers)
    int tn = t + 64;
    cNext = scand[base + (tn < U ? tn : 0)];
    iNext = sidx[base + (tn < U ? tn : 0)];

    int K = sK; if (K > KSEG) K = KSEG;
    bool kill = false;
#pragma unroll 4
    for (int j = w; j < K; j += GW)
      if (dist2(kc[j], c) <= RR2) kill = true;
    killM[w] = __ballot(kill);
    __syncthreads();
    if (w == 0) {
      unsigned long long killed = killM[0];
      for (int q = 1; q < GW; ++q) killed |= killM[q];
      bool alive = valid && !((killed >> lane) & 1ull);
      unsigned long long am = __ballot(alive);
      int Kl = sK;
      while (am) {
        int i = __ffsll((long long)am) - 1;
        float kx = __shfl(c.x, i), ky = __shfl(c.y, i), kz = __shfl(c.z, i), kw = __shfl(c.w, i);
        int ii = __shfl(cidx, i);
        float4 kf = make_float4(kx, ky, kz, kw);
        if (Kl < KSEG && lane == 0) {
          kc[Kl] = kf;
          segKeptCand[s * KSEG + Kl] = kf;
          segKeptIdx[s * KSEG + Kl] = ii;
        }
        ++Kl;
        if (alive && lane > i && dist2(kf, c) <= RR2) alive = false;
        am = __ballot(alive);
        am &= ~((i < 63) ? ((1ull << (i + 1)) - 1ull) : ~0ull);
      }
      if (lane == 0) sK = Kl;
    }
    __syncthreads();
  }
  if (threadIdx.x == 0) keptCntSeg[s] = (sK < KSEG) ? sK : KSEG;
}

// unify per-segment kept lists (segment-major; order within segment = greedy order)
__global__ void k_merge(int nseg, const float4* __restrict__ segKeptCand,
                        const int* __restrict__ segKeptIdx, const int* __restrict__ keptCntSeg,
                        float4* __restrict__ keptCand, int* __restrict__ keptIdx,
                        int* __restrict__ segKeptStart, int* __restrict__ segKeptCnt,
                        int* counters) {
  __shared__ int pre[NSEG_MAX + 1];
  if (threadIdx.x == 0) {
    int acc = 0;
    for (int s2 = 0; s2 < nseg; ++s2) {
      pre[s2] = acc;
      int cn = keptCntSeg[s2]; if (cn > KSEG) cn = KSEG;
      acc += cn;
    }
    pre[nseg] = acc;
    counters[C_KEPT] = (acc < KMAX) ? acc : KMAX;
  }
  __syncthreads();
  for (int s2 = 0; s2 < nseg; ++s2) {
    int cn = keptCntSeg[s2]; if (cn > KSEG) cn = KSEG;
    if (threadIdx.x == 0) { segKeptStart[s2] = pre[s2]; segKeptCnt[s2] = cn; }
    for (int j = threadIdx.x; j < cn; j += blockDim.x) {
      keptCand[pre[s2] + j] = segKeptCand[s2 * KSEG + j];
      keptIdx[pre[s2] + j] = segKeptIdx[s2 * KSEG + j];
    }
  }
}

// Each point -> FIRST kept (greedy order, own segment) within radius.
// Kept list + idx staged in LDS; x4-unrolled early-exit scan (wave-uniform j -> LDS broadcast);
// per-block LDS histogram -> one coalesced flush (no hot global atomics).
__global__ void __launch_bounds__(256) k_assign(
    const float* __restrict__ cc, const int* __restrict__ rs, int nrs, int N,
    const float4* __restrict__ keptCand, const int* __restrict__ keptIdx,
    const int* __restrict__ segKeptStart, const int* __restrict__ segKeptCnt,
    const int* __restrict__ counters,
    int* cntKept, int* countersW, int* __restrict__ assoInt,
    int* __restrict__ keptPos) {
  __shared__ float4 sk[ALDS];     // 32 KiB
  __shared__ int    sIx[ALDS];    // 8 KiB
  __shared__ int    shist[ALDS];  // 8 KiB
  __shared__ int    sUn;
  int Ktot = counters[C_KEPT];
  if (Ktot > KMAX) Ktot = KMAX;
  int Kl = Ktot < ALDS ? Ktot : ALDS;
  for (int j = threadIdx.x; j < Kl; j += blockDim.x) {
    sk[j] = keptCand[j];
    sIx[j] = keptIdx[j];
    shist[j] = 0;
  }
  if (threadIdx.x == 0) sUn = 0;
  __syncthreads();

  int i = blockIdx.x * blockDim.x + threadIdx.x;
  int bpos = -1, bidx = -1;
  bool active = i < N;
  if (active) {
    float4 p = make_float4(cc[3 * i], cc[3 * i + 1], cc[3 * i + 2], 0.f);
    int seg = 0;
    for (int t = 1; t < nrs - 1; ++t) seg += (i >= rs[t]) ? 1 : 0;
    int ks = segKeptStart[seg];
    int end = ks + segKeptCnt[seg];
    int lim = end < Kl ? end : Kl;
    int j = ks;
    for (; j + 3 < lim; j += 4) {     // 4 LDS reads per waitcnt -> 4x shorter chain
      bool h0 = dist2(sk[j], p) <= RR2;
      bool h1 = dist2(sk[j + 1], p) <= RR2;
      bool h2 = dist2(sk[j + 2], p) <= RR2;
      bool h3 = dist2(sk[j + 3], p) <= RR2;
      if (h0 | h1 | h2 | h3) { bpos = h0 ? j : h1 ? j + 1 : h2 ? j + 2 : j + 3; break; }
    }
    if (bpos < 0)
      for (; j < lim; ++j)
        if (dist2(sk[j], p) <= RR2) { bpos = j; break; }
    if (bpos < 0)                      // overflow tail beyond LDS (Ktot>ALDS): global
      for (; j < end; ++j)
        if (dist2(keptCand[j], p) <= RR2) { bpos = j; break; }
    if (bpos >= 0) {
      bidx = (bpos < Kl) ? sIx[bpos] : keptIdx[bpos];
      assoInt[i] = bidx;
      keptPos[i] = bpos;
      if (bpos < Kl) atomicAdd(&shist[bpos], 1);
      else atomicAdd(&cntKept[bpos], 1);
    } else {
      assoInt[i] = -1;
      keptPos[i] = -1;
      atomicAdd(&sUn, 1);
    }
  }
  __syncthreads();
  for (int j = threadIdx.x; j < Kl; j += blockDim.x) {
    int h = shist[j];
    if (h) atomicAdd(&cntKept[j], h);  // distinct addresses across lanes: parallel at L2
  }
  if (threadIdx.x == 0 && sUn) atomicAdd(&countersW[C_UN], sUn);
}

// rank kept by original index (asso values ascending); group 0 = unassigned if present
__global__ void k_rank(const int* __restrict__ keptIdx, int* counters,
                       const int* __restrict__ cntKept,
                       int* __restrict__ rankOfKept, int* __restrict__ groupCount) {
  __shared__ int sIdx[KMAX];   // 16 KiB
  int K = counters[C_KEPT];
  if (K > KMAX) K = KMAX;
  for (int j = threadIdx.x; j < K; j += blockDim.x) sIdx[j] = keptIdx[j];
  __syncthreads();
  int un = counters[C_UN];
  int hasUn = un > 0 ? 1 : 0;
  int gid = blockIdx.x * blockDim.x + threadIdx.x;
  int stride = gridDim.x * blockDim.x;
  if (gid == 0) {
    counters[C_HASUN] = hasUn;
    counters[C_G] = K + hasUn;
    if (hasUn) groupCount[0] = un;
  }
  for (int j = gid; j < K; j += stride) {
    int myIdx = sIdx[j];
    int r = hasUn;
    for (int j2 = 0; j2 < K; ++j2)
      r += (sIdx[j2] < myIdx) ? 1 : 0;
    rankOfKept[j] = r;
    groupCount[r] = cntKept[j];
  }
}

__global__ void k_pointrank(int N, const int* __restrict__ keptPos,
                            const int* __restrict__ rankOfKept,
                            const int* __restrict__ assoInt,
                            int* __restrict__ pointRank, float* __restrict__ outAsso) {
  int i = blockIdx.x * blockDim.x + threadIdx.x;
  if (i >= N) return;
  int p = keptPos[i];
  pointRank[i] = (p < 0) ? 0 : rankOfKept[p];
  outAsso[i] = (float)assoInt[i];
}

// parallel exclusive prefix over groupCount[0..G) (single block, 256 threads)
__global__ void k_scan(const int* __restrict__ counters, const int* __restrict__ groupCount,
                       int* __restrict__ starts) {
  __shared__ int partial[256];
  int G = counters[C_G];
  int t = threadIdx.x;
  const int PER = (KMAX + 2 + 255) / 256;
  int sum = 0;
  for (int q = 0; q < PER; ++q) {
    int idx = t * PER + q;
    if (idx < G) sum += groupCount[idx];
  }
  partial[t] = sum;
  __syncthreads();
  if (t == 0) {
    int acc = 0;
    for (int i = 0; i < 256; ++i) { int v = partial[i]; partial[i] = acc; acc += v; }
  }
  __syncthreads();
  int acc = partial[t];
  for (int q = 0; q < PER; ++q) {
    int idx = t * PER + q;
    if (idx < G) { starts[idx] = acc; acc += groupCount[idx]; }
  }
}

__global__ void k_psrs(int N, const int* __restrict__ counters, const int* __restrict__ starts,
                       float* __restrict__ outPsrs) {
  int p = blockIdx.x * blockDim.x + threadIdx.x;
  if (p > N) return;
  int G = counters[C_G];
  outPsrs[p] = (p < G) ? (float)starts[p] : (float)N;
}

// stable counting-sort scatter: one block per group, ballot prefix within chunks
__global__ void k_scatter(int N, const int* __restrict__ counters,
                          const int* __restrict__ pointRank, const int* __restrict__ starts,
                          int* __restrict__ order, float* __restrict__ outSids,
                          float* __restrict__ outBelongs) {
  int g = blockIdx.x;
  if (g >= counters[C_G]) return;
  int base = starts[g];
  __shared__ int wsum[4];
  int lane = threadIdx.x & 63, wv = threadIdx.x >> 6;
  for (int i0 = 0; i0 < N; i0 += 256) {
    int i = i0 + threadIdx.x;
    bool m = (i < N) && (pointRank[i] == g);
    unsigned long long bal = __ballot(m);
    int pw = __popcll(bal & ((1ull << lane) - 1ull));
    if (lane == 0) wsum[wv] = __popcll(bal);
    __syncthreads();
    int off = 0;
    for (int q = 0; q < wv; ++q) off += wsum[q];
    int tot = wsum[0] + wsum[1] + wsum[2] + wsum[3];
    if (m) {
      int pos = base + off + pw;
      order[pos] = i;
      outSids[pos] = (float)i;
      outBelongs[pos] = (float)g;
    }
    base += tot;
    __syncthreads();
  }
}

// flat grid-stride float4 row gather (F % 4 == 0 path)
__global__ void k_gather4(const float4* __restrict__ data4, const int* __restrict__ order,
                          int F4, int total4, float4* __restrict__ out4) {
  int stride = gridDim.x * blockDim.x;
  for (int idx = blockIdx.x * blockDim.x + threadIdx.x; idx < total4; idx += stride) {
    int row = idx / F4;
    int col = idx - row * F4;
    out4[idx] = data4[(size_t)order[row] * F4 + col];
  }
}

__global__ void k_gather(const float* __restrict__ data, const int* __restrict__ order,
                         int F, float* __restrict__ out) {
  int row = blockIdx.x;
  int src = order[row];
  for (int f = threadIdx.x; f < F; f += blockDim.x)
    out[(size_t)row * F + f] = data[(size_t)src * F + f];
}

extern "C" void kernel_launch(void* const* d_in, const int* in_sizes, int n_in,
                              void* d_out, int out_size, void* d_ws, size_t ws_size,
                              hipStream_t stream) {
  const float* data  = (const float*)d_in[0];
  const float* cc    = (const float*)d_in[1];
  const float* betas = (const float*)d_in[2];
  const int*   rs    = (const int*)d_in[3];
  int nrs = in_sizes[3];
  int N   = in_sizes[2];           // betas is (N,1)
  int F   = in_sizes[0] / N;       // 128
  int nseg = nrs - 1; if (nseg < 1) nseg = 1; if (nseg > NSEG_MAX) nseg = NSEG_MAX;

  float* out = (float*)d_out;
  float* outSdata   = out;
  float* outPsrs    = outSdata + (size_t)N * F;
  float* outSids    = outPsrs + (N + 1);
  float* outAsso    = outSids + N;
  float* outBelongs = outAsso + N;

  char* p = (char*)d_ws;
  auto alloc = [&](size_t bytes) { void* r = (void*)p; p += (bytes + 255) & ~(size_t)255; return r; };
  int*    counters     = (int*)alloc(64 * 4);
  float4* ucand        = (float4*)alloc((size_t)N * 16);
  int*    uidx         = (int*)alloc((size_t)N * 4);
  int*    ubkt         = (int*)alloc((size_t)N * 4);
  float4* scand        = (float4*)alloc((size_t)N * 16);
  int*    sidx         = (int*)alloc((size_t)N * 4);
  int*    bucketCnt    = (int*)alloc(NBTOT * 4);
  int*    bucketStart  = (int*)alloc((NBTOT + 1) * 4);
  int*    bucketFill   = (int*)alloc(NBTOT * 4);
  float4* segKeptCand  = (float4*)alloc((size_t)NSEG_MAX * KSEG * 16);
  int*    segKeptIdx   = (int*)alloc((size_t)NSEG_MAX * KSEG * 4);
  int*    keptCntSeg   = (int*)alloc(NSEG_MAX * 4);
  int*    segKeptStart = (int*)alloc(NSEG_MAX * 4);
  int*    segKeptCnt   = (int*)alloc(NSEG_MAX * 4);
  float4* keptCand     = (float4*)alloc(KMAX * 16);
  int*    keptIdx      = (int*)alloc(KMAX * 4);
  int*    rankOfKept   = (int*)alloc(KMAX * 4);
  int*    cntKept      = (int*)alloc(KMAX * 4);
  int*    groupCount   = (int*)alloc((KMAX + 2) * 4);
  int*    starts       = (int*)alloc((KMAX + 2) * 4);
  int*    assoInt      = (int*)alloc((size_t)N * 4);
  int*    keptPos      = (int*)alloc((size_t)N * 4);
  int*    pointRank    = (int*)alloc((size_t)N * 4);
  int*    order        = (int*)alloc((size_t)N * 4);

  int nb = (N + 255) / 256;

  k_init<<<(NBTOT + 255) / 256, 256, 0, stream>>>(counters, cntKept, groupCount,
                                                  bucketCnt, bucketFill);

  k_compact<<<nb, 256, 0, stream>>>(betas, cc, rs, nrs, N, ucand, uidx, ubkt,
                                    bucketCnt, &counters[C_U0]);

  k_bucketscan<<<1, 256, 0, stream>>>(bucketCnt, bucketStart);

  k_bucketscatter<<<nb, 256, 0, stream>>>(counters, ucand, uidx, ubkt,
                                          bucketStart, bucketFill, scand, sidx);

  k_bucketsort<<<NBTOT / 256, 256, 0, stream>>>(bucketCnt, bucketStart, scand, sidx);

  k_greedy<<<nseg, 256, 0, stream>>>(scand, sidx, bucketStart,
                                     segKeptCand, segKeptIdx, keptCntSeg);

  k_merge<<<1, 256, 0, stream>>>(nseg, segKeptCand, segKeptIdx, keptCntSeg,
                                 keptCand, keptIdx, segKeptStart, segKeptCnt, counters);

  k_assign<<<nb, 256, 0, stream>>>(cc, rs, nrs, N, keptCand, keptIdx,
                                   segKeptStart, segKeptCnt, counters, cntKept, counters,
                                   assoInt, keptPos);

  k_rank<<<32, 256, 0, stream>>>(keptIdx, counters, cntKept, rankOfKept, groupCount);

  k_pointrank<<<nb, 256, 0, stream>>>(N, keptPos, rankOfKept, assoInt, pointRank, outAsso);

  k_scan<<<1, 256, 0, stream>>>(counters, groupCount, starts);

  k_psrs<<<(N + 256) / 256, 256, 0, stream>>>(N, counters, starts, outPsrs);

  k_scatter<<<KMAX + 1, 256, 0, stream>>>(N, counters, pointRank, starts, order,
                                          outSids, outBelongs);

  if (F % 4 == 0) {
    int F4 = F / 4;
    int total4 = N * F4;
    k_gather4<<<2048, 256, 0, stream>>>((const float4*)data, order, F4, total4,
                                        (float4*)outSdata);
  } else {
    k_gather<<<N, 128, 0, stream>>>(data, order, F, outSdata);
  }
}

// Round 4
// 701.744 us; speedup vs baseline: 1.7786x; 1.4786x over previous
//
#include <hip/hip_runtime.h>
#include <cstdint>

#define THRESH 0.8f
#define RR2    2.25f
#define KMAX   4096      // unified kept cap
#define KSEG   2048      // per-segment kept cap (LDS-resident in greedy)
#define ALDS   2048      // kept staged in LDS for assign
#define NB     4096      // beta buckets per segment
#define NSEG_MAX 4
#define NBTOT  (NB * NSEG_MAX)

#define GW     4         // greedy waves per block
#define SCHUNK 1024      // points per chunk in the counting-sort scatter

// counters (ints): [0]=keptCnt [1]=cntUnassigned [2]=G [3]=hasUn [8]=U (candidate count)
#define C_KEPT  0
#define C_UN    1
#define C_G     2
#define C_HASUN 3
#define C_U0    8

// f32, no FMA contraction, left-assoc: matches numpy/XLA (x*x + y*y) + z*z
__device__ __forceinline__ float dist2(const float4 a, const float4 b) {
#pragma clang fp contract(off)
  float dx = a.x - b.x;
  float dy = a.y - b.y;
  float dz = a.z - b.z;
  return dx * dx + dy * dy + dz * dz;
}

__global__ void k_init(int* counters, int* cntKept, int* groupCount,
                       int* bucketCnt, int* bucketFill) {
  int i = blockIdx.x * blockDim.x + threadIdx.x;
  if (i < 64) counters[i] = 0;
  if (i < KMAX) cntKept[i] = 0;
  if (i < KMAX + 2) groupCount[i] = 0;
  if (i < NBTOT) { bucketCnt[i] = 0; bucketFill[i] = 0; }
}

__device__ __forceinline__ int beta_bucket(float b) {
  int t = (int)((b - 0.8f) * 20480.0f);   // [0.8,1) -> [0,4096)
  return t < 0 ? 0 : (t > NB - 1 ? NB - 1 : t);
}

// ord-bucket = seg*NB + (NB-1 - beta_bucket): ascending ord == segment-major, beta-desc
__global__ void k_compact(const float* __restrict__ betas, const float* __restrict__ cc,
                          const int* __restrict__ rs, int nrs, int N,
                          float4* __restrict__ ucand, int* __restrict__ uidx,
                          int* __restrict__ ubkt, int* bucketCnt, int* mCnt) {
  int i = blockIdx.x * blockDim.x + threadIdx.x;
  if (i >= N) return;
  float b = betas[i];
  if (b >= THRESH) {
    int slot = atomicAdd(mCnt, 1);
    ucand[slot] = make_float4(cc[3 * i], cc[3 * i + 1], cc[3 * i + 2], b);
    uidx[slot] = i;
    int s = 0;
    for (int t = 1; t < nrs - 1; ++t) s += (i >= rs[t]) ? 1 : 0;
    int ord = s * NB + (NB - 1 - beta_bucket(b));
    ubkt[slot] = ord;
    atomicAdd(&bucketCnt[ord], 1);
  }
}

// ascending prefix sum over NBTOT ord-buckets; bucketStart[NBTOT] = total
__global__ void k_bucketscan(const int* __restrict__ bucketCnt, int* __restrict__ bucketStart) {
  __shared__ int partial[256];
  int t = threadIdx.x;
  const int PER = NBTOT / 256;   // 64
  int sum = 0;
  for (int q = 0; q < PER; ++q) sum += bucketCnt[t * PER + q];
  partial[t] = sum;
  __syncthreads();
  if (t == 0) {
    int acc = 0;
    for (int i = 0; i < 256; ++i) { int v = partial[i]; partial[i] = acc; acc += v; }
    bucketStart[NBTOT] = acc;
  }
  __syncthreads();
  int acc = partial[t];
  for (int q = 0; q < PER; ++q) {
    int b = t * PER + q;
    bucketStart[b] = acc;
    acc += bucketCnt[b];
  }
}

__global__ void k_bucketscatter(const int* __restrict__ counters,
                                const float4* __restrict__ ucand, const int* __restrict__ uidx,
                                const int* __restrict__ ubkt,
                                const int* __restrict__ bucketStart, int* bucketFill,
                                float4* __restrict__ scand, int* __restrict__ sidx) {
  int i = blockIdx.x * blockDim.x + threadIdx.x;
  if (i >= counters[C_U0]) return;
  int b = ubkt[i];
  int pos = bucketStart[b] + atomicAdd(&bucketFill[b], 1);
  scand[pos] = ucand[i];
  sidx[pos] = uidx[i];
}

// one thread per ord-bucket: insertion sort by (beta desc, idx asc) -> exact per-segment order
__global__ void k_bucketsort(const int* __restrict__ bucketCnt, const int* __restrict__ bucketStart,
                             float4* __restrict__ scand, int* __restrict__ sidx) {
  int b = blockIdx.x * blockDim.x + threadIdx.x;
  if (b >= NBTOT) return;
  int start = bucketStart[b];
  int end = start + bucketCnt[b];
  for (int a = start + 1; a < end; ++a) {
    float4 v = scand[a]; int vi = sidx[a];
    int p = a - 1;
    while (p >= start && (scand[p].w < v.w || (scand[p].w == v.w && sidx[p] > vi))) {
      scand[p + 1] = scand[p]; sidx[p + 1] = sidx[p];
      --p;
    }
    scand[p + 1] = v; sidx[p + 1] = vi;
  }
}

// Cooperative exact greedy (R3: known-good). GW=4 waves; register double-buffer
// prefetch of next 64-candidate chunk; wave-0 shuffle-broadcast resolve.
__global__ void __launch_bounds__(256) k_greedy(
    const float4* __restrict__ scand, const int* __restrict__ sidx,
    const int* __restrict__ bucketStart,
    float4* __restrict__ segKeptCand, int* __restrict__ segKeptIdx,
    int* __restrict__ keptCntSeg) {
  __shared__ float4 kc[KSEG];                  // 32 KiB
  __shared__ unsigned long long killM[GW];
  __shared__ int sK;
  int s = blockIdx.x;
  int base = bucketStart[s * NB];
  int U = bucketStart[(s + 1) * NB] - base;
  int lane = threadIdx.x & 63, w = threadIdx.x >> 6;
  if (threadIdx.x == 0) sK = 0;
  __syncthreads();

  // per-wave private prefetch of chunk 0 (each wave holds its own copy)
  int t0 = lane;
  float4 cNext = scand[base + (t0 < U ? t0 : 0)];
  int    iNext = sidx[base + (t0 < U ? t0 : 0)];

  for (int c0 = 0; c0 < U; c0 += 64) {
    int t = c0 + lane;
    bool valid = t < U;
    float4 c = cNext;
    int cidx = iNext;

    // prefetch next chunk (in flight across kill + resolve + barriers)
    int tn = t + 64;
    cNext = scand[base + (tn < U ? tn : 0)];
    iNext = sidx[base + (tn < U ? tn : 0)];

    int K = sK; if (K > KSEG) K = KSEG;
    bool kill = false;
#pragma unroll 4
    for (int j = w; j < K; j += GW)
      if (dist2(kc[j], c) <= RR2) kill = true;
    killM[w] = __ballot(kill);
    __syncthreads();
    if (w == 0) {
      unsigned long long killed = killM[0];
      for (int q = 1; q < GW; ++q) killed |= killM[q];
      bool alive = valid && !((killed >> lane) & 1ull);
      unsigned long long am = __ballot(alive);
      int Kl = sK;
      while (am) {
        int i = __ffsll((long long)am) - 1;
        float kx = __shfl(c.x, i), ky = __shfl(c.y, i), kz = __shfl(c.z, i), kw = __shfl(c.w, i);
        int ii = __shfl(cidx, i);
        float4 kf = make_float4(kx, ky, kz, kw);
        if (Kl < KSEG && lane == 0) {
          kc[Kl] = kf;
          segKeptCand[s * KSEG + Kl] = kf;
          segKeptIdx[s * KSEG + Kl] = ii;
        }
        ++Kl;
        if (alive && lane > i && dist2(kf, c) <= RR2) alive = false;
        am = __ballot(alive);
        am &= ~((i < 63) ? ((1ull << (i + 1)) - 1ull) : ~0ull);
      }
      if (lane == 0) sK = Kl;
    }
    __syncthreads();
  }
  if (threadIdx.x == 0) keptCntSeg[s] = (sK < KSEG) ? sK : KSEG;
}

// unify per-segment kept lists (segment-major; order within segment = greedy order)
__global__ void k_merge(int nseg, const float4* __restrict__ segKeptCand,
                        const int* __restrict__ segKeptIdx, const int* __restrict__ keptCntSeg,
                        float4* __restrict__ keptCand, int* __restrict__ keptIdx,
                        int* __restrict__ segKeptStart, int* __restrict__ segKeptCnt,
                        int* counters) {
  __shared__ int pre[NSEG_MAX + 1];
  if (threadIdx.x == 0) {
    int acc = 0;
    for (int s2 = 0; s2 < nseg; ++s2) {
      pre[s2] = acc;
      int cn = keptCntSeg[s2]; if (cn > KSEG) cn = KSEG;
      acc += cn;
    }
    pre[nseg] = acc;
    counters[C_KEPT] = (acc < KMAX) ? acc : KMAX;
  }
  __syncthreads();
  for (int s2 = 0; s2 < nseg; ++s2) {
    int cn = keptCntSeg[s2]; if (cn > KSEG) cn = KSEG;
    if (threadIdx.x == 0) { segKeptStart[s2] = pre[s2]; segKeptCnt[s2] = cn; }
    for (int j = threadIdx.x; j < cn; j += blockDim.x) {
      keptCand[pre[s2] + j] = segKeptCand[s2 * KSEG + j];
      keptIdx[pre[s2] + j] = segKeptIdx[s2 * KSEG + j];
    }
  }
}

// Each point -> FIRST kept (greedy order, own segment) within radius.
__global__ void __launch_bounds__(256) k_assign(
    const float* __restrict__ cc, const int* __restrict__ rs, int nrs, int N,
    const float4* __restrict__ keptCand, const int* __restrict__ keptIdx,
    const int* __restrict__ segKeptStart, const int* __restrict__ segKeptCnt,
    const int* __restrict__ counters,
    int* cntKept, int* countersW, int* __restrict__ assoInt,
    int* __restrict__ keptPos) {
  __shared__ float4 sk[ALDS];     // 32 KiB
  __shared__ int    sIx[ALDS];    // 8 KiB
  __shared__ int    shist[ALDS];  // 8 KiB
  __shared__ int    sUn;
  int Ktot = counters[C_KEPT];
  if (Ktot > KMAX) Ktot = KMAX;
  int Kl = Ktot < ALDS ? Ktot : ALDS;
  for (int j = threadIdx.x; j < Kl; j += blockDim.x) {
    sk[j] = keptCand[j];
    sIx[j] = keptIdx[j];
    shist[j] = 0;
  }
  if (threadIdx.x == 0) sUn = 0;
  __syncthreads();

  int i = blockIdx.x * blockDim.x + threadIdx.x;
  int bpos = -1, bidx = -1;
  bool active = i < N;
  if (active) {
    float4 p = make_float4(cc[3 * i], cc[3 * i + 1], cc[3 * i + 2], 0.f);
    int seg = 0;
    for (int t = 1; t < nrs - 1; ++t) seg += (i >= rs[t]) ? 1 : 0;
    int ks = segKeptStart[seg];
    int end = ks + segKeptCnt[seg];
    int lim = end < Kl ? end : Kl;
    int j = ks;
    for (; j + 3 < lim; j += 4) {     // 4 LDS reads per waitcnt -> 4x shorter chain
      bool h0 = dist2(sk[j], p) <= RR2;
      bool h1 = dist2(sk[j + 1], p) <= RR2;
      bool h2 = dist2(sk[j + 2], p) <= RR2;
      bool h3 = dist2(sk[j + 3], p) <= RR2;
      if (h0 | h1 | h2 | h3) { bpos = h0 ? j : h1 ? j + 1 : h2 ? j + 2 : j + 3; break; }
    }
    if (bpos < 0)
      for (; j < lim; ++j)
        if (dist2(sk[j], p) <= RR2) { bpos = j; break; }
    if (bpos < 0)                      // overflow tail beyond LDS (Ktot>ALDS): global
      for (; j < end; ++j)
        if (dist2(keptCand[j], p) <= RR2) { bpos = j; break; }
    if (bpos >= 0) {
      bidx = (bpos < Kl) ? sIx[bpos] : keptIdx[bpos];
      assoInt[i] = bidx;
      keptPos[i] = bpos;
      if (bpos < Kl) atomicAdd(&shist[bpos], 1);
      else atomicAdd(&cntKept[bpos], 1);
    } else {
      assoInt[i] = -1;
      keptPos[i] = -1;
      atomicAdd(&sUn, 1);
    }
  }
  __syncthreads();
  for (int j = threadIdx.x; j < Kl; j += blockDim.x) {
    int h = shist[j];
    if (h) atomicAdd(&cntKept[j], h);  // distinct addresses across lanes: parallel at L2
  }
  if (threadIdx.x == 0 && sUn) atomicAdd(&countersW[C_UN], sUn);
}

// rank kept by original index (asso values ascending); group 0 = unassigned if present
__global__ void k_rank(const int* __restrict__ keptIdx, int* counters,
                       const int* __restrict__ cntKept,
                       int* __restrict__ rankOfKept, int* __restrict__ groupCount) {
  __shared__ int sIdx[KMAX];   // 16 KiB
  int K = counters[C_KEPT];
  if (K > KMAX) K = KMAX;
  for (int j = threadIdx.x; j < K; j += blockDim.x) sIdx[j] = keptIdx[j];
  __syncthreads();
  int un = counters[C_UN];
  int hasUn = un > 0 ? 1 : 0;
  int gid = blockIdx.x * blockDim.x + threadIdx.x;
  int stride = gridDim.x * blockDim.x;
  if (gid == 0) {
    counters[C_HASUN] = hasUn;
    counters[C_G] = K + hasUn;
    if (hasUn) groupCount[0] = un;
  }
  for (int j = gid; j < K; j += stride) {
    int myIdx = sIdx[j];
    int r = hasUn;
    for (int j2 = 0; j2 < K; ++j2)
      r += (sIdx[j2] < myIdx) ? 1 : 0;
    rankOfKept[j] = r;
    groupCount[r] = cntKept[j];
  }
}

__global__ void k_pointrank(int N, const int* __restrict__ keptPos,
                            const int* __restrict__ rankOfKept,
                            const int* __restrict__ assoInt,
                            int* __restrict__ pointRank, float* __restrict__ outAsso) {
  int i = blockIdx.x * blockDim.x + threadIdx.x;
  if (i >= N) return;
  int p = keptPos[i];
  pointRank[i] = (p < 0) ? 0 : rankOfKept[p];
  outAsso[i] = (float)assoInt[i];
}

// parallel exclusive prefix over groupCount[0..G) (single block, 256 threads)
__global__ void k_scan(const int* __restrict__ counters, const int* __restrict__ groupCount,
                       int* __restrict__ starts) {
  __shared__ int partial[256];
  int G = counters[C_G];
  int t = threadIdx.x;
  const int PER = (KMAX + 2 + 255) / 256;
  int sum = 0;
  for (int q = 0; q < PER; ++q) {
    int idx = t * PER + q;
    if (idx < G) sum += groupCount[idx];
  }
  partial[t] = sum;
  __syncthreads();
  if (t == 0) {
    int acc = 0;
    for (int i = 0; i < 256; ++i) { int v = partial[i]; partial[i] = acc; acc += v; }
  }
  __syncthreads();
  int acc = partial[t];
  for (int q = 0; q < PER; ++q) {
    int idx = t * PER + q;
    if (idx < G) { starts[idx] = acc; acc += groupCount[idx]; }
  }
}

__global__ void k_psrs(int N, const int* __restrict__ counters, const int* __restrict__ starts,
                       float* __restrict__ outPsrs) {
  int p = blockIdx.x * blockDim.x + threadIdx.x;
  if (p > N) return;
  int G = counters[C_G];
  outPsrs[p] = (p < G) ? (float)starts[p] : (float)N;
}

// ---- 3-pass stable counting-sort scatter (replaces O(G*N) per-group scan) ----
// R3 rocprof: old k_scatter = 403us, VALUBusy 3.3%, 4097 blocks each scanning all
// of pointRank (O(G*N) reads, ~186K barriers). New: O(N + G*C).

// pass 1: per-chunk rank histogram (chunk c = points [c*SCHUNK, (c+1)*SCHUNK))
__global__ void __launch_bounds__(256) k_hist(
    int N, int C, const int* __restrict__ counters,
    const int* __restrict__ pointRank, int* __restrict__ chunkHist) {
  __shared__ int h[KMAX + 2];   // 16 KiB
  int G = counters[C_G];
  for (int g = threadIdx.x; g < G; g += 256) h[g] = 0;
  __syncthreads();
  int c = blockIdx.x;
  int i0 = c * SCHUNK;
  for (int q = 0; q < SCHUNK; q += 256) {
    int i = i0 + q + threadIdx.x;
    if (i < N) atomicAdd(&h[pointRank[i]], 1);
  }
  __syncthreads();
  for (int g = threadIdx.x; g < G; g += 256)
    chunkHist[(size_t)g * C + c] = h[g];
}

// pass 2: in-place exclusive scan over chunks per group, seeded with starts[g]
__global__ void k_chunkbase(int C, const int* __restrict__ counters,
                            const int* __restrict__ starts, int* __restrict__ chunkHist) {
  int g = blockIdx.x * blockDim.x + threadIdx.x;
  if (g >= counters[C_G]) return;
  int acc = starts[g];
  size_t base = (size_t)g * C;
  for (int c = 0; c < C; ++c) {
    int v = chunkHist[base + c];
    chunkHist[base + c] = acc;
    acc += v;
  }
}

// pass 3: scatter; stability = ascending batch order + ascending tid within batch
__global__ void __launch_bounds__(256) k_scatter2(
    int N, int C, const int* __restrict__ counters,
    const int* __restrict__ pointRank, const int* __restrict__ chunkBase,
    int* __restrict__ order, float* __restrict__ outSids,
    float* __restrict__ outBelongs) {
  __shared__ int baseL[KMAX + 2];   // 16 KiB running per-group write cursor
  __shared__ int ranks[256];
  int G = counters[C_G];
  int c = blockIdx.x;
  for (int g = threadIdx.x; g < G; g += 256)
    baseL[g] = chunkBase[(size_t)g * C + c];
  __syncthreads();
  int i0 = c * SCHUNK;
  int t = threadIdx.x;
  for (int q = 0; q < SCHUNK; q += 256) {
    int i = i0 + q + t;
    int r = -1;
    if (i < N) r = pointRank[i];
    ranks[t] = r;
    __syncthreads();
    if (i < N) {
      int cnt = 0;
      for (int j = 0; j < 256; ++j)          // uniform j -> LDS broadcast read
        cnt += (j < t && ranks[j] == r) ? 1 : 0;
      int pos = baseL[r] + cnt;
      order[pos] = i;
      outSids[pos] = (float)i;
      outBelongs[pos] = (float)r;
    }
    __syncthreads();
    if (i < N) atomicAdd(&baseL[r], 1);       // advance cursors for next batch
    __syncthreads();
  }
}

// flat grid-stride float4 row gather (F % 4 == 0 path)
__global__ void k_gather4(const float4* __restrict__ data4, const int* __restrict__ order,
                          int F4, int total4, float4* __restrict__ out4) {
  int stride = gridDim.x * blockDim.x;
  for (int idx = blockIdx.x * blockDim.x + threadIdx.x; idx < total4; idx += stride) {
    int row = idx / F4;
    int col = idx - row * F4;
    out4[idx] = data4[(size_t)order[row] * F4 + col];
  }
}

__global__ void k_gather(const float* __restrict__ data, const int* __restrict__ order,
                         int F, float* __restrict__ out) {
  int row = blockIdx.x;
  int src = order[row];
  for (int f = threadIdx.x; f < F; f += blockDim.x)
    out[(size_t)row * F + f] = data[(size_t)src * F + f];
}

extern "C" void kernel_launch(void* const* d_in, const int* in_sizes, int n_in,
                              void* d_out, int out_size, void* d_ws, size_t ws_size,
                              hipStream_t stream) {
  const float* data  = (const float*)d_in[0];
  const float* cc    = (const float*)d_in[1];
  const float* betas = (const float*)d_in[2];
  const int*   rs    = (const int*)d_in[3];
  int nrs = in_sizes[3];
  int N   = in_sizes[2];           // betas is (N,1)
  int F   = in_sizes[0] / N;       // 128
  int nseg = nrs - 1; if (nseg < 1) nseg = 1; if (nseg > NSEG_MAX) nseg = NSEG_MAX;
  int C   = (N + SCHUNK - 1) / SCHUNK;

  float* out = (float*)d_out;
  float* outSdata   = out;
  float* outPsrs    = outSdata + (size_t)N * F;
  float* outSids    = outPsrs + (N + 1);
  float* outAsso    = outSids + N;
  float* outBelongs = outAsso + N;

  char* p = (char*)d_ws;
  auto alloc = [&](size_t bytes) { void* r = (void*)p; p += (bytes + 255) & ~(size_t)255; return r; };
  int*    counters     = (int*)alloc(64 * 4);
  float4* ucand        = (float4*)alloc((size_t)N * 16);
  int*    uidx         = (int*)alloc((size_t)N * 4);
  int*    ubkt         = (int*)alloc((size_t)N * 4);
  float4* scand        = (float4*)alloc((size_t)N * 16);
  int*    sidx         = (int*)alloc((size_t)N * 4);
  int*    bucketCnt    = (int*)alloc(NBTOT * 4);
  int*    bucketStart  = (int*)alloc((NBTOT + 1) * 4);
  int*    bucketFill   = (int*)alloc(NBTOT * 4);
  float4* segKeptCand  = (float4*)alloc((size_t)NSEG_MAX * KSEG * 16);
  int*    segKeptIdx   = (int*)alloc((size_t)NSEG_MAX * KSEG * 4);
  int*    keptCntSeg   = (int*)alloc(NSEG_MAX * 4);
  int*    segKeptStart = (int*)alloc(NSEG_MAX * 4);
  int*    segKeptCnt   = (int*)alloc(NSEG_MAX * 4);
  float4* keptCand     = (float4*)alloc(KMAX * 16);
  int*    keptIdx      = (int*)alloc(KMAX * 4);
  int*    rankOfKept   = (int*)alloc(KMAX * 4);
  int*    cntKept      = (int*)alloc(KMAX * 4);
  int*    groupCount   = (int*)alloc((KMAX + 2) * 4);
  int*    starts       = (int*)alloc((KMAX + 2) * 4);
  int*    assoInt      = (int*)alloc((size_t)N * 4);
  int*    keptPos      = (int*)alloc((size_t)N * 4);
  int*    pointRank    = (int*)alloc((size_t)N * 4);
  int*    order        = (int*)alloc((size_t)N * 4);
  int*    chunkHist    = (int*)alloc((size_t)(KMAX + 2) * C * 4);

  int nb = (N + 255) / 256;

  k_init<<<(NBTOT + 255) / 256, 256, 0, stream>>>(counters, cntKept, groupCount,
                                                  bucketCnt, bucketFill);

  k_compact<<<nb, 256, 0, stream>>>(betas, cc, rs, nrs, N, ucand, uidx, ubkt,
                                    bucketCnt, &counters[C_U0]);

  k_bucketscan<<<1, 256, 0, stream>>>(bucketCnt, bucketStart);

  k_bucketscatter<<<nb, 256, 0, stream>>>(counters, ucand, uidx, ubkt,
                                          bucketStart, bucketFill, scand, sidx);

  k_bucketsort<<<NBTOT / 256, 256, 0, stream>>>(bucketCnt, bucketStart, scand, sidx);

  k_greedy<<<nseg, 256, 0, stream>>>(scand, sidx, bucketStart,
                                     segKeptCand, segKeptIdx, keptCntSeg);

  k_merge<<<1, 256, 0, stream>>>(nseg, segKeptCand, segKeptIdx, keptCntSeg,
                                 keptCand, keptIdx, segKeptStart, segKeptCnt, counters);

  k_assign<<<nb, 256, 0, stream>>>(cc, rs, nrs, N, keptCand, keptIdx,
                                   segKeptStart, segKeptCnt, counters, cntKept, counters,
                                   assoInt, keptPos);

  k_rank<<<32, 256, 0, stream>>>(keptIdx, counters, cntKept, rankOfKept, groupCount);

  k_pointrank<<<nb, 256, 0, stream>>>(N, keptPos, rankOfKept, assoInt, pointRank, outAsso);

  k_scan<<<1, 256, 0, stream>>>(counters, groupCount, starts);

  k_psrs<<<(N + 256) / 256, 256, 0, stream>>>(N, counters, starts, outPsrs);

  k_hist<<<C, 256, 0, stream>>>(N, C, counters, pointRank, chunkHist);

  k_chunkbase<<<(KMAX + 2 + 255) / 256, 256, 0, stream>>>(C, counters, starts, chunkHist);

  k_scatter2<<<C, 256, 0, stream>>>(N, C, counters, pointRank, chunkHist,
                                    order, outSids, outBelongs);

  if (F % 4 == 0) {
    int F4 = F / 4;
    int total4 = N * F4;
    k_gather4<<<2048, 256, 0, stream>>>((const float4*)data, order, F4, total4,
                                        (float4*)outSdata);
  } else {
    k_gather<<<N, 128, 0, stream>>>(data, order, F, outSdata);
  }
}

// Round 6
// 557.420 us; speedup vs baseline: 2.2391x; 1.2589x over previous
//
#include <hip/hip_runtime.h>
#include <cstdint>

#define THRESH 0.8f
#define RR2    2.25f
#define KMAX   4096      // unified kept cap
#define KSEG   2048      // per-segment kept cap (LDS-resident in greedy)
#define ALDS   2048      // kept staged in LDS for assign
#define NB     4096      // beta buckets per segment
#define NSEG_MAX 4
#define NBTOT  (NB * NSEG_MAX)

#define GW     4         // greedy waves per block
#define GH     4         // candidate halves per chunk (4 x 64 = 256 cands/chunk)
#define SCHUNK 1024      // points per chunk in the counting-sort scatter

// counters (ints): [0]=keptCnt [1]=cntUnassigned [2]=G [3]=hasUn [8]=U (candidate count)
#define C_KEPT  0
#define C_UN    1
#define C_G     2
#define C_HASUN 3
#define C_U0    8

// f32, no FMA contraction, left-assoc: matches numpy/XLA (x*x + y*y) + z*z
__device__ __forceinline__ float dist2(const float4 a, const float4 b) {
#pragma clang fp contract(off)
  float dx = a.x - b.x;
  float dy = a.y - b.y;
  float dz = a.z - b.z;
  return dx * dx + dy * dy + dz * dz;
}

__global__ void k_init(int* counters, int* cntKept, int* groupCount,
                       int* bucketCnt, int* bucketFill) {
  int i = blockIdx.x * blockDim.x + threadIdx.x;
  if (i < 64) counters[i] = 0;
  if (i < KMAX) cntKept[i] = 0;
  if (i < KMAX + 2) groupCount[i] = 0;
  if (i < NBTOT) { bucketCnt[i] = 0; bucketFill[i] = 0; }
}

__device__ __forceinline__ int beta_bucket(float b) {
  int t = (int)((b - 0.8f) * 20480.0f);   // [0.8,1) -> [0,4096)
  return t < 0 ? 0 : (t > NB - 1 ? NB - 1 : t);
}

// ord-bucket = seg*NB + (NB-1 - beta_bucket): ascending ord == segment-major, beta-desc
__global__ void k_compact(const float* __restrict__ betas, const float* __restrict__ cc,
                          const int* __restrict__ rs, int nrs, int N,
                          float4* __restrict__ ucand, int* __restrict__ uidx,
                          int* __restrict__ ubkt, int* bucketCnt, int* mCnt) {
  int i = blockIdx.x * blockDim.x + threadIdx.x;
  if (i >= N) return;
  float b = betas[i];
  if (b >= THRESH) {
    int slot = atomicAdd(mCnt, 1);
    ucand[slot] = make_float4(cc[3 * i], cc[3 * i + 1], cc[3 * i + 2], b);
    uidx[slot] = i;
    int s = 0;
    for (int t = 1; t < nrs - 1; ++t) s += (i >= rs[t]) ? 1 : 0;
    int ord = s * NB + (NB - 1 - beta_bucket(b));
    ubkt[slot] = ord;
    atomicAdd(&bucketCnt[ord], 1);
  }
}

// ascending prefix sum over NBTOT ord-buckets; bucketStart[NBTOT] = total
__global__ void k_bucketscan(const int* __restrict__ bucketCnt, int* __restrict__ bucketStart) {
  __shared__ int partial[256];
  int t = threadIdx.x;
  const int PER = NBTOT / 256;   // 64
  int sum = 0;
  for (int q = 0; q < PER; ++q) sum += bucketCnt[t * PER + q];
  partial[t] = sum;
  __syncthreads();
  if (t == 0) {
    int acc = 0;
    for (int i = 0; i < 256; ++i) { int v = partial[i]; partial[i] = acc; acc += v; }
    bucketStart[NBTOT] = acc;
  }
  __syncthreads();
  int acc = partial[t];
  for (int q = 0; q < PER; ++q) {
    int b = t * PER + q;
    bucketStart[b] = acc;
    acc += bucketCnt[b];
  }
}

__global__ void k_bucketscatter(const int* __restrict__ counters,
                                const float4* __restrict__ ucand, const int* __restrict__ uidx,
                                const int* __restrict__ ubkt,
                                const int* __restrict__ bucketStart, int* bucketFill,
                                float4* __restrict__ scand, int* __restrict__ sidx) {
  int i = blockIdx.x * blockDim.x + threadIdx.x;
  if (i >= counters[C_U0]) return;
  int b = ubkt[i];
  int pos = bucketStart[b] + atomicAdd(&bucketFill[b], 1);
  scand[pos] = ucand[i];
  sidx[pos] = uidx[i];
}

// one thread per ord-bucket: insertion sort by (beta desc, idx asc) -> exact per-segment order
__global__ void k_bucketsort(const int* __restrict__ bucketCnt, const int* __restrict__ bucketStart,
                             float4* __restrict__ scand, int* __restrict__ sidx) {
  int b = blockIdx.x * blockDim.x + threadIdx.x;
  if (b >= NBTOT) return;
  int start = bucketStart[b];
  int end = start + bucketCnt[b];
  for (int a = start + 1; a < end; ++a) {
    float4 v = scand[a]; int vi = sidx[a];
    int p = a - 1;
    while (p >= start && (scand[p].w < v.w || (scand[p].w == v.w && sidx[p] > vi))) {
      scand[p + 1] = scand[p]; sidx[p + 1] = sidx[p];
      --p;
    }
    scand[p + 1] = v; sidx[p + 1] = vi;
  }
}

// Cooperative exact greedy. R4 rocprof: per-chunk cost is irreducible overhead
// (2 barriers + vmcnt-drained load latency), so amortize: 256 candidates/chunk
// (4 halves x 64, 4 per lane), chunk count 312 -> 78.
//  - kill phase: verbatim R3 structure, 4 kill flags per lane (replicated cands).
//  - resolve: R1's verified 2-half cross-delta-kill generalized to 4 halves,
//    statically unrolled (no runtime-indexed arrays -> stays in registers).
__global__ void __launch_bounds__(256) k_greedy(
    const float4* __restrict__ scand, const int* __restrict__ sidx,
    const int* __restrict__ bucketStart,
    float4* __restrict__ segKeptCand, int* __restrict__ segKeptIdx,
    int* __restrict__ keptCntSeg) {
  __shared__ float4 kc[KSEG];                  // 32 KiB
  __shared__ unsigned long long killM[GH][GW];
  __shared__ int sK;
  int s = blockIdx.x;
  int base = bucketStart[s * NB];
  int U = bucketStart[(s + 1) * NB] - base;
  int lane = threadIdx.x & 63, w = threadIdx.x >> 6;
  if (threadIdx.x == 0) sK = 0;
  __syncthreads();

  // prefetch chunk 0: every wave holds an identical copy of all 256 candidates
  float4 cN[GH]; int iN[GH];
#pragma unroll
  for (int h = 0; h < GH; ++h) {
    int t = h * 64 + lane;
    cN[h] = scand[base + (t < U ? t : 0)];
    iN[h] = sidx[base + (t < U ? t : 0)];
  }

  for (int c0 = 0; c0 < U; c0 += GH * 64) {
    float4 c[GH]; int ci[GH]; bool valid[GH];
#pragma unroll
    for (int h = 0; h < GH; ++h) {
      c[h] = cN[h]; ci[h] = iN[h];
      valid[h] = (c0 + h * 64 + lane) < U;
    }
    // prefetch next chunk (issues early; hides latency under kill work)
#pragma unroll
    for (int h = 0; h < GH; ++h) {
      int t = c0 + GH * 64 + h * 64 + lane;
      cN[h] = scand[base + (t < U ? t : 0)];
      iN[h] = sidx[base + (t < U ? t : 0)];
    }

    // kill vs existing kept: wave w checks kept j = w, w+GW, ...
    int K = sK; if (K > KSEG) K = KSEG;
    bool kill[GH];
#pragma unroll
    for (int h = 0; h < GH; ++h) kill[h] = false;
    for (int j = w; j < K; j += GW) {
      float4 k0 = kc[j];
#pragma unroll
      for (int h = 0; h < GH; ++h)
        if (dist2(k0, c[h]) <= RR2) kill[h] = true;
    }
#pragma unroll
    for (int h = 0; h < GH; ++h) {
      unsigned long long b = __ballot(kill[h]);
      if (lane == 0) killM[h][w] = b;
    }
    __syncthreads();

    // wave 0: resolve survivors half by half, exact sorted order
    if (w == 0) {
      int Kl = sK;
      bool al[GH];
#pragma unroll
      for (int h = 0; h < GH; ++h) {
        unsigned long long killed = killM[h][0];
#pragma unroll
        for (int q = 1; q < GW; ++q) killed |= killM[h][q];
        al[h] = valid[h] && !((killed >> lane) & 1ull);
      }
#pragma unroll
      for (int h = 0; h < GH; ++h) {
        unsigned long long am = __ballot(al[h]);
        while (am) {
          int i = __ffsll((long long)am) - 1;
          float kx = __shfl(c[h].x, i), ky = __shfl(c[h].y, i),
                kz = __shfl(c[h].z, i), kw = __shfl(c[h].w, i);
          int ii = __shfl(ci[h], i);
          float4 kf = make_float4(kx, ky, kz, kw);
          if (Kl < KSEG && lane == 0) {
            kc[Kl] = kf;
            segKeptCand[s * KSEG + Kl] = kf;
            segKeptIdx[s * KSEG + Kl] = ii;
          }
          ++Kl;
          // kill later candidates in this half (lane > i) ...
          if (al[h] && lane > i && dist2(kf, c[h]) <= RR2) al[h] = false;
          // ... and in all later halves (all positions are later in sort order)
#pragma unroll
          for (int h2 = h + 1; h2 < GH; ++h2)
            if (al[h2] && dist2(kf, c[h2]) <= RR2) al[h2] = false;
          am = __ballot(al[h]);
          am &= ~((i < 63) ? ((1ull << (i + 1)) - 1ull) : ~0ull);
        }
      }
      if (lane == 0) sK = Kl;
    }
    __syncthreads();
  }
  if (threadIdx.x == 0) keptCntSeg[s] = (sK < KSEG) ? sK : KSEG;
}

// unify per-segment kept lists (segment-major; order within segment = greedy order)
__global__ void k_merge(int nseg, const float4* __restrict__ segKeptCand,
                        const int* __restrict__ segKeptIdx, const int* __restrict__ keptCntSeg,
                        float4* __restrict__ keptCand, int* __restrict__ keptIdx,
                        int* __restrict__ segKeptStart, int* __restrict__ segKeptCnt,
                        int* counters) {
  __shared__ int pre[NSEG_MAX + 1];
  if (threadIdx.x == 0) {
    int acc = 0;
    for (int s2 = 0; s2 < nseg; ++s2) {
      pre[s2] = acc;
      int cn = keptCntSeg[s2]; if (cn > KSEG) cn = KSEG;
      acc += cn;
    }
    pre[nseg] = acc;
    counters[C_KEPT] = (acc < KMAX) ? acc : KMAX;
  }
  __syncthreads();
  for (int s2 = 0; s2 < nseg; ++s2) {
    int cn = keptCntSeg[s2]; if (cn > KSEG) cn = KSEG;
    if (threadIdx.x == 0) { segKeptStart[s2] = pre[s2]; segKeptCnt[s2] = cn; }
    for (int j = threadIdx.x; j < cn; j += blockDim.x) {
      keptCand[pre[s2] + j] = segKeptCand[s2 * KSEG + j];
      keptIdx[pre[s2] + j] = segKeptIdx[s2 * KSEG + j];
    }
  }
}

// Each point -> FIRST kept (greedy order, own segment) within radius.
__global__ void __launch_bounds__(256) k_assign(
    const float* __restrict__ cc, const int* __restrict__ rs, int nrs, int N,
    const float4* __restrict__ keptCand, const int* __restrict__ keptIdx,
    const int* __restrict__ segKeptStart, const int* __restrict__ segKeptCnt,
    const int* __restrict__ counters,
    int* cntKept, int* countersW, int* __restrict__ assoInt,
    int* __restrict__ keptPos) {
  __shared__ float4 sk[ALDS];     // 32 KiB
  __shared__ int    sIx[ALDS];    // 8 KiB
  __shared__ int    shist[ALDS];  // 8 KiB
  __shared__ int    sUn;
  int Ktot = counters[C_KEPT];
  if (Ktot > KMAX) Ktot = KMAX;
  int Kl = Ktot < ALDS ? Ktot : ALDS;
  for (int j = threadIdx.x; j < Kl; j += blockDim.x) {
    sk[j] = keptCand[j];
    sIx[j] = keptIdx[j];
    shist[j] = 0;
  }
  if (threadIdx.x == 0) sUn = 0;
  __syncthreads();

  int i = blockIdx.x * blockDim.x + threadIdx.x;
  int bpos = -1, bidx = -1;
  bool active = i < N;
  if (active) {
    float4 p = make_float4(cc[3 * i], cc[3 * i + 1], cc[3 * i + 2], 0.f);
    int seg = 0;
    for (int t = 1; t < nrs - 1; ++t) seg += (i >= rs[t]) ? 1 : 0;
    int ks = segKeptStart[seg];
    int end = ks + segKeptCnt[seg];
    int lim = end < Kl ? end : Kl;
    int j = ks;
    for (; j + 3 < lim; j += 4) {     // 4 LDS reads per waitcnt -> 4x shorter chain
      bool h0 = dist2(sk[j], p) <= RR2;
      bool h1 = dist2(sk[j + 1], p) <= RR2;
      bool h2 = dist2(sk[j + 2], p) <= RR2;
      bool h3 = dist2(sk[j + 3], p) <= RR2;
      if (h0 | h1 | h2 | h3) { bpos = h0 ? j : h1 ? j + 1 : h2 ? j + 2 : j + 3; break; }
    }
    if (bpos < 0)
      for (; j < lim; ++j)
        if (dist2(sk[j], p) <= RR2) { bpos = j; break; }
    if (bpos < 0)                      // overflow tail beyond LDS (Ktot>ALDS): global
      for (; j < end; ++j)
        if (dist2(keptCand[j], p) <= RR2) { bpos = j; break; }
    if (bpos >= 0) {
      bidx = (bpos < Kl) ? sIx[bpos] : keptIdx[bpos];
      assoInt[i] = bidx;
      keptPos[i] = bpos;
      if (bpos < Kl) atomicAdd(&shist[bpos], 1);
      else atomicAdd(&cntKept[bpos], 1);
    } else {
      assoInt[i] = -1;
      keptPos[i] = -1;
      atomicAdd(&sUn, 1);
    }
  }
  __syncthreads();
  for (int j = threadIdx.x; j < Kl; j += blockDim.x) {
    int h = shist[j];
    if (h) atomicAdd(&cntKept[j], h);  // distinct addresses across lanes: parallel at L2
  }
  if (threadIdx.x == 0 && sUn) atomicAdd(&countersW[C_UN], sUn);
}

// rank kept by original index (asso values ascending); group 0 = unassigned if present
__global__ void k_rank(const int* __restrict__ keptIdx, int* counters,
                       const int* __restrict__ cntKept,
                       int* __restrict__ rankOfKept, int* __restrict__ groupCount) {
  __shared__ int sIdx[KMAX];   // 16 KiB
  int K = counters[C_KEPT];
  if (K > KMAX) K = KMAX;
  for (int j = threadIdx.x; j < K; j += blockDim.x) sIdx[j] = keptIdx[j];
  __syncthreads();
  int un = counters[C_UN];
  int hasUn = un > 0 ? 1 : 0;
  int gid = blockIdx.x * blockDim.x + threadIdx.x;
  int stride = gridDim.x * blockDim.x;
  if (gid == 0) {
    counters[C_HASUN] = hasUn;
    counters[C_G] = K + hasUn;
    if (hasUn) groupCount[0] = un;
  }
  for (int j = gid; j < K; j += stride) {
    int myIdx = sIdx[j];
    int r = hasUn;
    for (int j2 = 0; j2 < K; ++j2)
      r += (sIdx[j2] < myIdx) ? 1 : 0;
    rankOfKept[j] = r;
    groupCount[r] = cntKept[j];
  }
}

__global__ void k_pointrank(int N, const int* __restrict__ keptPos,
                            const int* __restrict__ rankOfKept,
                            const int* __restrict__ assoInt,
                            int* __restrict__ pointRank, float* __restrict__ outAsso) {
  int i = blockIdx.x * blockDim.x + threadIdx.x;
  if (i >= N) return;
  int p = keptPos[i];
  pointRank[i] = (p < 0) ? 0 : rankOfKept[p];
  outAsso[i] = (float)assoInt[i];
}

// parallel exclusive prefix over groupCount[0..G) (single block, 256 threads)
__global__ void k_scan(const int* __restrict__ counters, const int* __restrict__ groupCount,
                       int* __restrict__ starts) {
  __shared__ int partial[256];
  int G = counters[C_G];
  int t = threadIdx.x;
  const int PER = (KMAX + 2 + 255) / 256;
  int sum = 0;
  for (int q = 0; q < PER; ++q) {
    int idx = t * PER + q;
    if (idx < G) sum += groupCount[idx];
  }
  partial[t] = sum;
  __syncthreads();
  if (t == 0) {
    int acc = 0;
    for (int i = 0; i < 256; ++i) { int v = partial[i]; partial[i] = acc; acc += v; }
  }
  __syncthreads();
  int acc = partial[t];
  for (int q = 0; q < PER; ++q) {
    int idx = t * PER + q;
    if (idx < G) { starts[idx] = acc; acc += groupCount[idx]; }
  }
}

__global__ void k_psrs(int N, const int* __restrict__ counters, const int* __restrict__ starts,
                       float* __restrict__ outPsrs) {
  int p = blockIdx.x * blockDim.x + threadIdx.x;
  if (p > N) return;
  int G = counters[C_G];
  outPsrs[p] = (p < G) ? (float)starts[p] : (float)N;
}

// ---- 3-pass stable counting-sort scatter (R4: verified, replaced O(G*N) scan) ----

// pass 1: per-chunk rank histogram (chunk c = points [c*SCHUNK, (c+1)*SCHUNK))
__global__ void __launch_bounds__(256) k_hist(
    int N, int C, const int* __restrict__ counters,
    const int* __restrict__ pointRank, int* __restrict__ chunkHist) {
  __shared__ int h[KMAX + 2];   // 16 KiB
  int G = counters[C_G];
  for (int g = threadIdx.x; g < G; g += 256) h[g] = 0;
  __syncthreads();
  int c = blockIdx.x;
  int i0 = c * SCHUNK;
  for (int q = 0; q < SCHUNK; q += 256) {
    int i = i0 + q + threadIdx.x;
    if (i < N) atomicAdd(&h[pointRank[i]], 1);
  }
  __syncthreads();
  for (int g = threadIdx.x; g < G; g += 256)
    chunkHist[(size_t)g * C + c] = h[g];
}

// pass 2: in-place exclusive scan over chunks per group, seeded with starts[g]
__global__ void k_chunkbase(int C, const int* __restrict__ counters,
                            const int* __restrict__ starts, int* __restrict__ chunkHist) {
  int g = blockIdx.x * blockDim.x + threadIdx.x;
  if (g >= counters[C_G]) return;
  int acc = starts[g];
  size_t base = (size_t)g * C;
  for (int c = 0; c < C; ++c) {
    int v = chunkHist[base + c];
    chunkHist[base + c] = acc;
    acc += v;
  }
}

// pass 3: scatter; stability = ascending batch order + ascending tid within batch
__global__ void __launch_bounds__(256) k_scatter2(
    int N, int C, const int* __restrict__ counters,
    const int* __restrict__ pointRank, const int* __restrict__ chunkBase,
    int* __restrict__ order, float* __restrict__ outSids,
    float* __restrict__ outBelongs) {
  __shared__ int baseL[KMAX + 2];   // 16 KiB running per-group write cursor
  __shared__ int ranks[256];
  int G = counters[C_G];
  int c = blockIdx.x;
  for (int g = threadIdx.x; g < G; g += 256)
    baseL[g] = chunkBase[(size_t)g * C + c];
  __syncthreads();
  int i0 = c * SCHUNK;
  int t = threadIdx.x;
  for (int q = 0; q < SCHUNK; q += 256) {
    int i = i0 + q + t;
    int r = -1;
    if (i < N) r = pointRank[i];
    ranks[t] = r;
    __syncthreads();
    if (i < N) {
      int cnt = 0;
      for (int j = 0; j < 256; ++j)          // uniform j -> LDS broadcast read
        cnt += (j < t && ranks[j] == r) ? 1 : 0;
      int pos = baseL[r] + cnt;
      order[pos] = i;
      outSids[pos] = (float)i;
      outBelongs[pos] = (float)r;
    }
    __syncthreads();
    if (i < N) atomicAdd(&baseL[r], 1);       // advance cursors for next batch
    __syncthreads();
  }
}

// flat grid-stride float4 row gather (F % 4 == 0 path)
__global__ void k_gather4(const float4* __restrict__ data4, const int* __restrict__ order,
                          int F4, int total4, float4* __restrict__ out4) {
  int stride = gridDim.x * blockDim.x;
  for (int idx = blockIdx.x * blockDim.x + threadIdx.x; idx < total4; idx += stride) {
    int row = idx / F4;
    int col = idx - row * F4;
    out4[idx] = data4[(size_t)order[row] * F4 + col];
  }
}

__global__ void k_gather(const float* __restrict__ data, const int* __restrict__ order,
                         int F, float* __restrict__ out) {
  int row = blockIdx.x;
  int src = order[row];
  for (int f = threadIdx.x; f < F; f += blockDim.x)
    out[(size_t)row * F + f] = data[(size_t)src * F + f];
}

extern "C" void kernel_launch(void* const* d_in, const int* in_sizes, int n_in,
                              void* d_out, int out_size, void* d_ws, size_t ws_size,
                              hipStream_t stream) {
  const float* data  = (const float*)d_in[0];
  const float* cc    = (const float*)d_in[1];
  const float* betas = (const float*)d_in[2];
  const int*   rs    = (const int*)d_in[3];
  int nrs = in_sizes[3];
  int N   = in_sizes[2];           // betas is (N,1)
  int F   = in_sizes[0] / N;       // 128
  int nseg = nrs - 1; if (nseg < 1) nseg = 1; if (nseg > NSEG_MAX) nseg = NSEG_MAX;
  int C   = (N + SCHUNK - 1) / SCHUNK;

  float* out = (float*)d_out;
  float* outSdata   = out;
  float* outPsrs    = outSdata + (size_t)N * F;
  float* outSids    = outPsrs + (N + 1);
  float* outAsso    = outSids + N;
  float* outBelongs = outAsso + N;

  char* p = (char*)d_ws;
  auto alloc = [&](size_t bytes) { void* r = (void*)p; p += (bytes + 255) & ~(size_t)255; return r; };
  int*    counters     = (int*)alloc(64 * 4);
  float4* ucand        = (float4*)alloc((size_t)N * 16);
  int*    uidx         = (int*)alloc((size_t)N * 4);
  int*    ubkt         = (int*)alloc((size_t)N * 4);
  float4* scand        = (float4*)alloc((size_t)N * 16);
  int*    sidx         = (int*)alloc((size_t)N * 4);
  int*    bucketCnt    = (int*)alloc(NBTOT * 4);
  int*    bucketStart  = (int*)alloc((NBTOT + 1) * 4);
  int*    bucketFill   = (int*)alloc(NBTOT * 4);
  float4* segKeptCand  = (float4*)alloc((size_t)NSEG_MAX * KSEG * 16);
  int*    segKeptIdx   = (int*)alloc((size_t)NSEG_MAX * KSEG * 4);
  int*    keptCntSeg   = (int*)alloc(NSEG_MAX * 4);
  int*    segKeptStart = (int*)alloc(NSEG_MAX * 4);
  int*    segKeptCnt   = (int*)alloc(NSEG_MAX * 4);
  float4* keptCand     = (float4*)alloc(KMAX * 16);
  int*    keptIdx      = (int*)alloc(KMAX * 4);
  int*    rankOfKept   = (int*)alloc(KMAX * 4);
  int*    cntKept      = (int*)alloc(KMAX * 4);
  int*    groupCount   = (int*)alloc((KMAX + 2) * 4);
  int*    starts       = (int*)alloc((KMAX + 2) * 4);
  int*    assoInt      = (int*)alloc((size_t)N * 4);
  int*    keptPos      = (int*)alloc((size_t)N * 4);
  int*    pointRank    = (int*)alloc((size_t)N * 4);
  int*    order        = (int*)alloc((size_t)N * 4);
  int*    chunkHist    = (int*)alloc((size_t)(KMAX + 2) * C * 4);

  int nb = (N + 255) / 256;

  k_init<<<(NBTOT + 255) / 256, 256, 0, stream>>>(counters, cntKept, groupCount,
                                                  bucketCnt, bucketFill);

  k_compact<<<nb, 256, 0, stream>>>(betas, cc, rs, nrs, N, ucand, uidx, ubkt,
                                    bucketCnt, &counters[C_U0]);

  k_bucketscan<<<1, 256, 0, stream>>>(bucketCnt, bucketStart);

  k_bucketscatter<<<nb, 256, 0, stream>>>(counters, ucand, uidx, ubkt,
                                          bucketStart, bucketFill, scand, sidx);

  k_bucketsort<<<NBTOT / 256, 256, 0, stream>>>(bucketCnt, bucketStart, scand, sidx);

  k_greedy<<<nseg, 256, 0, stream>>>(scand, sidx, bucketStart,
                                     segKeptCand, segKeptIdx, keptCntSeg);

  k_merge<<<1, 256, 0, stream>>>(nseg, segKeptCand, segKeptIdx, keptCntSeg,
                                 keptCand, keptIdx, segKeptStart, segKeptCnt, counters);

  k_assign<<<nb, 256, 0, stream>>>(cc, rs, nrs, N, keptCand, keptIdx,
                                   segKeptStart, segKeptCnt, counters, cntKept, counters,
                                   assoInt, keptPos);

  k_rank<<<32, 256, 0, stream>>>(keptIdx, counters, cntKept, rankOfKept, groupCount);

  k_pointrank<<<nb, 256, 0, stream>>>(N, keptPos, rankOfKept, assoInt, pointRank, outAsso);

  k_scan<<<1, 256, 0, stream>>>(counters, groupCount, starts);

  k_psrs<<<(N + 256) / 256, 256, 0, stream>>>(N, counters, starts, outPsrs);

  k_hist<<<C, 256, 0, stream>>>(N, C, counters, pointRank, chunkHist);

  k_chunkbase<<<(KMAX + 2 + 255) / 256, 256, 0, stream>>>(C, counters, starts, chunkHist);

  k_scatter2<<<C, 256, 0, stream>>>(N, C, counters, pointRank, chunkHist,
                                    order, outSids, outBelongs);

  if (F % 4 == 0) {
    int F4 = F / 4;
    int total4 = N * F4;
    k_gather4<<<2048, 256, 0, stream>>>((const float4*)data, order, F4, total4,
                                        (float4*)outSdata);
  } else {
    k_gather<<<N, 128, 0, stream>>>(data, order, F, outSdata);
  }
}

// Round 7
// 542.007 us; speedup vs baseline: 2.3027x; 1.0284x over previous
//
#include <hip/hip_runtime.h>
#include <cstdint>

#define THRESH 0.8f
#define RR2    2.25f
#define KMAX   4096      // unified kept cap
#define KSEG   2048      // per-segment kept cap (LDS-resident in greedy)
#define ALDS   2048      // kept staged in LDS for assign
#define NB     4096      // beta buckets per segment
#define NSEG_MAX 4
#define NBTOT  (NB * NSEG_MAX)

#define GW     4         // greedy waves per block
#define GH     8         // candidate sub-groups per chunk (8 x 64 = 512 cands/chunk)
#define SCHUNK 1024      // points per chunk in the counting-sort scatter

// counters (ints): [0]=keptCnt [1]=cntUnassigned [2]=G [3]=hasUn [8]=U (candidate count)
#define C_KEPT  0
#define C_UN    1
#define C_G     2
#define C_HASUN 3
#define C_U0    8

// f32, no FMA contraction, left-assoc: matches numpy/XLA (x*x + y*y) + z*z
__device__ __forceinline__ float dist2(const float4 a, const float4 b) {
#pragma clang fp contract(off)
  float dx = a.x - b.x;
  float dy = a.y - b.y;
  float dz = a.z - b.z;
  return dx * dx + dy * dy + dz * dz;
}

__global__ void k_init(int* counters, int* cntKept, int* groupCount,
                       int* bucketCnt, int* bucketFill) {
  int i = blockIdx.x * blockDim.x + threadIdx.x;
  if (i < 64) counters[i] = 0;
  if (i < KMAX) cntKept[i] = 0;
  if (i < KMAX + 2) groupCount[i] = 0;
  if (i < NBTOT) { bucketCnt[i] = 0; bucketFill[i] = 0; }
}

__device__ __forceinline__ int beta_bucket(float b) {
  int t = (int)((b - 0.8f) * 20480.0f);   // [0.8,1) -> [0,4096)
  return t < 0 ? 0 : (t > NB - 1 ? NB - 1 : t);
}

// ord-bucket = seg*NB + (NB-1 - beta_bucket): ascending ord == segment-major, beta-desc
__global__ void k_compact(const float* __restrict__ betas, const float* __restrict__ cc,
                          const int* __restrict__ rs, int nrs, int N,
                          float4* __restrict__ ucand, int* __restrict__ uidx,
                          int* __restrict__ ubkt, int* bucketCnt, int* mCnt) {
  int i = blockIdx.x * blockDim.x + threadIdx.x;
  if (i >= N) return;
  float b = betas[i];
  if (b >= THRESH) {
    int slot = atomicAdd(mCnt, 1);
    ucand[slot] = make_float4(cc[3 * i], cc[3 * i + 1], cc[3 * i + 2], b);
    uidx[slot] = i;
    int s = 0;
    for (int t = 1; t < nrs - 1; ++t) s += (i >= rs[t]) ? 1 : 0;
    int ord = s * NB + (NB - 1 - beta_bucket(b));
    ubkt[slot] = ord;
    atomicAdd(&bucketCnt[ord], 1);
  }
}

// ascending prefix sum over NBTOT ord-buckets; bucketStart[NBTOT] = total
__global__ void k_bucketscan(const int* __restrict__ bucketCnt, int* __restrict__ bucketStart) {
  __shared__ int partial[256];
  int t = threadIdx.x;
  const int PER = NBTOT / 256;   // 64
  int sum = 0;
  for (int q = 0; q < PER; ++q) sum += bucketCnt[t * PER + q];
  partial[t] = sum;
  __syncthreads();
  if (t == 0) {
    int acc = 0;
    for (int i = 0; i < 256; ++i) { int v = partial[i]; partial[i] = acc; acc += v; }
    bucketStart[NBTOT] = acc;
  }
  __syncthreads();
  int acc = partial[t];
  for (int q = 0; q < PER; ++q) {
    int b = t * PER + q;
    bucketStart[b] = acc;
    acc += bucketCnt[b];
  }
}

__global__ void k_bucketscatter(const int* __restrict__ counters,
                                const float4* __restrict__ ucand, const int* __restrict__ uidx,
                                const int* __restrict__ ubkt,
                                const int* __restrict__ bucketStart, int* bucketFill,
                                float4* __restrict__ scand, int* __restrict__ sidx) {
  int i = blockIdx.x * blockDim.x + threadIdx.x;
  if (i >= counters[C_U0]) return;
  int b = ubkt[i];
  int pos = bucketStart[b] + atomicAdd(&bucketFill[b], 1);
  scand[pos] = ucand[i];
  sidx[pos] = uidx[i];
}

// one thread per ord-bucket: insertion sort by (beta desc, idx asc) -> exact per-segment order
__global__ void k_bucketsort(const int* __restrict__ bucketCnt, const int* __restrict__ bucketStart,
                             float4* __restrict__ scand, int* __restrict__ sidx) {
  int b = blockIdx.x * blockDim.x + threadIdx.x;
  if (b >= NBTOT) return;
  int start = bucketStart[b];
  int end = start + bucketCnt[b];
  for (int a = start + 1; a < end; ++a) {
    float4 v = scand[a]; int vi = sidx[a];
    int p = a - 1;
    while (p >= start && (scand[p].w < v.w || (scand[p].w == v.w && sidx[p] > vi))) {
      scand[p + 1] = scand[p]; sidx[p + 1] = sidx[p];
      --p;
    }
    scand[p + 1] = v; sidx[p + 1] = vi;
  }
}

// Cooperative exact greedy. R6 measured: per-chunk fixed overhead (2 barriers w/
// vmcnt drain + serial resolve) amortizes sub-linearly: 39.7 cy/cand @64-chunk,
// 22.1 @256-chunk. R7: GH=8 (512 cands/chunk, chunks 79->40), same structure.
//  - kill phase: 8 dist2 per kc[j] LDS broadcast read (more ILP per ds_read).
//  - resolve: statically-unrolled cross-half delta-kill, verified at GH=2 (R1)
//    and GH=4 (R6), extended to 8.
__global__ void __launch_bounds__(256) k_greedy(
    const float4* __restrict__ scand, const int* __restrict__ sidx,
    const int* __restrict__ bucketStart,
    float4* __restrict__ segKeptCand, int* __restrict__ segKeptIdx,
    int* __restrict__ keptCntSeg) {
  __shared__ float4 kc[KSEG];                  // 32 KiB
  __shared__ unsigned long long killM[GH][GW];
  __shared__ int sK;
  int s = blockIdx.x;
  int base = bucketStart[s * NB];
  int U = bucketStart[(s + 1) * NB] - base;
  int lane = threadIdx.x & 63, w = threadIdx.x >> 6;
  if (threadIdx.x == 0) sK = 0;
  __syncthreads();

  // prefetch chunk 0: every wave holds an identical copy of all 512 candidates
  float4 cN[GH]; int iN[GH];
#pragma unroll
  for (int h = 0; h < GH; ++h) {
    int t = h * 64 + lane;
    cN[h] = scand[base + (t < U ? t : 0)];
    iN[h] = sidx[base + (t < U ? t : 0)];
  }

  for (int c0 = 0; c0 < U; c0 += GH * 64) {
    float4 c[GH]; int ci[GH]; bool valid[GH];
#pragma unroll
    for (int h = 0; h < GH; ++h) {
      c[h] = cN[h]; ci[h] = iN[h];
      valid[h] = (c0 + h * 64 + lane) < U;
    }
    // prefetch next chunk (issues early; hides latency under kill work)
#pragma unroll
    for (int h = 0; h < GH; ++h) {
      int t = c0 + GH * 64 + h * 64 + lane;
      cN[h] = scand[base + (t < U ? t : 0)];
      iN[h] = sidx[base + (t < U ? t : 0)];
    }

    // kill vs existing kept: wave w checks kept j = w, w+GW, ...
    int K = sK; if (K > KSEG) K = KSEG;
    bool kill[GH];
#pragma unroll
    for (int h = 0; h < GH; ++h) kill[h] = false;
    for (int j = w; j < K; j += GW) {
      float4 k0 = kc[j];
#pragma unroll
      for (int h = 0; h < GH; ++h)
        if (dist2(k0, c[h]) <= RR2) kill[h] = true;
    }
#pragma unroll
    for (int h = 0; h < GH; ++h) {
      unsigned long long b = __ballot(kill[h]);
      if (lane == 0) killM[h][w] = b;
    }
    __syncthreads();

    // wave 0: resolve survivors sub-group by sub-group, exact sorted order
    if (w == 0) {
      int Kl = sK;
      bool al[GH];
#pragma unroll
      for (int h = 0; h < GH; ++h) {
        unsigned long long killed = killM[h][0];
#pragma unroll
        for (int q = 1; q < GW; ++q) killed |= killM[h][q];
        al[h] = valid[h] && !((killed >> lane) & 1ull);
      }
#pragma unroll
      for (int h = 0; h < GH; ++h) {
        unsigned long long am = __ballot(al[h]);
        while (am) {
          int i = __ffsll((long long)am) - 1;
          float kx = __shfl(c[h].x, i), ky = __shfl(c[h].y, i),
                kz = __shfl(c[h].z, i), kw = __shfl(c[h].w, i);
          int ii = __shfl(ci[h], i);
          float4 kf = make_float4(kx, ky, kz, kw);
          if (Kl < KSEG && lane == 0) {
            kc[Kl] = kf;
            segKeptCand[s * KSEG + Kl] = kf;
            segKeptIdx[s * KSEG + Kl] = ii;
          }
          ++Kl;
          // kill later candidates in this sub-group (lane > i) ...
          if (al[h] && lane > i && dist2(kf, c[h]) <= RR2) al[h] = false;
          // ... and in all later sub-groups (later in sort order)
#pragma unroll
          for (int h2 = h + 1; h2 < GH; ++h2)
            if (al[h2] && dist2(kf, c[h2]) <= RR2) al[h2] = false;
          am = __ballot(al[h]);
          am &= ~((i < 63) ? ((1ull << (i + 1)) - 1ull) : ~0ull);
        }
      }
      if (lane == 0) sK = Kl;
    }
    __syncthreads();
  }
  if (threadIdx.x == 0) keptCntSeg[s] = (sK < KSEG) ? sK : KSEG;
}

// unify per-segment kept lists (segment-major; order within segment = greedy order)
__global__ void k_merge(int nseg, const float4* __restrict__ segKeptCand,
                        const int* __restrict__ segKeptIdx, const int* __restrict__ keptCntSeg,
                        float4* __restrict__ keptCand, int* __restrict__ keptIdx,
                        int* __restrict__ segKeptStart, int* __restrict__ segKeptCnt,
                        int* counters) {
  __shared__ int pre[NSEG_MAX + 1];
  if (threadIdx.x == 0) {
    int acc = 0;
    for (int s2 = 0; s2 < nseg; ++s2) {
      pre[s2] = acc;
      int cn = keptCntSeg[s2]; if (cn > KSEG) cn = KSEG;
      acc += cn;
    }
    pre[nseg] = acc;
    counters[C_KEPT] = (acc < KMAX) ? acc : KMAX;
  }
  __syncthreads();
  for (int s2 = 0; s2 < nseg; ++s2) {
    int cn = keptCntSeg[s2]; if (cn > KSEG) cn = KSEG;
    if (threadIdx.x == 0) { segKeptStart[s2] = pre[s2]; segKeptCnt[s2] = cn; }
    for (int j = threadIdx.x; j < cn; j += blockDim.x) {
      keptCand[pre[s2] + j] = segKeptCand[s2 * KSEG + j];
      keptIdx[pre[s2] + j] = segKeptIdx[s2 * KSEG + j];
    }
  }
}

// Each point -> FIRST kept (greedy order, own segment) within radius.
__global__ void __launch_bounds__(256) k_assign(
    const float* __restrict__ cc, const int* __restrict__ rs, int nrs, int N,
    const float4* __restrict__ keptCand, const int* __restrict__ keptIdx,
    const int* __restrict__ segKeptStart, const int* __restrict__ segKeptCnt,
    const int* __restrict__ counters,
    int* cntKept, int* countersW, int* __restrict__ assoInt,
    int* __restrict__ keptPos) {
  __shared__ float4 sk[ALDS];     // 32 KiB
  __shared__ int    sIx[ALDS];    // 8 KiB
  __shared__ int    shist[ALDS];  // 8 KiB
  __shared__ int    sUn;
  int Ktot = counters[C_KEPT];
  if (Ktot > KMAX) Ktot = KMAX;
  int Kl = Ktot < ALDS ? Ktot : ALDS;
  for (int j = threadIdx.x; j < Kl; j += blockDim.x) {
    sk[j] = keptCand[j];
    sIx[j] = keptIdx[j];
    shist[j] = 0;
  }
  if (threadIdx.x == 0) sUn = 0;
  __syncthreads();

  int i = blockIdx.x * blockDim.x + threadIdx.x;
  int bpos = -1, bidx = -1;
  bool active = i < N;
  if (active) {
    float4 p = make_float4(cc[3 * i], cc[3 * i + 1], cc[3 * i + 2], 0.f);
    int seg = 0;
    for (int t = 1; t < nrs - 1; ++t) seg += (i >= rs[t]) ? 1 : 0;
    int ks = segKeptStart[seg];
    int end = ks + segKeptCnt[seg];
    int lim = end < Kl ? end : Kl;
    int j = ks;
    for (; j + 3 < lim; j += 4) {     // 4 LDS reads per waitcnt -> 4x shorter chain
      bool h0 = dist2(sk[j], p) <= RR2;
      bool h1 = dist2(sk[j + 1], p) <= RR2;
      bool h2 = dist2(sk[j + 2], p) <= RR2;
      bool h3 = dist2(sk[j + 3], p) <= RR2;
      if (h0 | h1 | h2 | h3) { bpos = h0 ? j : h1 ? j + 1 : h2 ? j + 2 : j + 3; break; }
    }
    if (bpos < 0)
      for (; j < lim; ++j)
        if (dist2(sk[j], p) <= RR2) { bpos = j; break; }
    if (bpos < 0)                      // overflow tail beyond LDS (Ktot>ALDS): global
      for (; j < end; ++j)
        if (dist2(keptCand[j], p) <= RR2) { bpos = j; break; }
    if (bpos >= 0) {
      bidx = (bpos < Kl) ? sIx[bpos] : keptIdx[bpos];
      assoInt[i] = bidx;
      keptPos[i] = bpos;
      if (bpos < Kl) atomicAdd(&shist[bpos], 1);
      else atomicAdd(&cntKept[bpos], 1);
    } else {
      assoInt[i] = -1;
      keptPos[i] = -1;
      atomicAdd(&sUn, 1);
    }
  }
  __syncthreads();
  for (int j = threadIdx.x; j < Kl; j += blockDim.x) {
    int h = shist[j];
    if (h) atomicAdd(&cntKept[j], h);  // distinct addresses across lanes: parallel at L2
  }
  if (threadIdx.x == 0 && sUn) atomicAdd(&countersW[C_UN], sUn);
}

// rank kept by original index (asso values ascending); group 0 = unassigned if present
__global__ void k_rank(const int* __restrict__ keptIdx, int* counters,
                       const int* __restrict__ cntKept,
                       int* __restrict__ rankOfKept, int* __restrict__ groupCount) {
  __shared__ int sIdx[KMAX];   // 16 KiB
  int K = counters[C_KEPT];
  if (K > KMAX) K = KMAX;
  for (int j = threadIdx.x; j < K; j += blockDim.x) sIdx[j] = keptIdx[j];
  __syncthreads();
  int un = counters[C_UN];
  int hasUn = un > 0 ? 1 : 0;
  int gid = blockIdx.x * blockDim.x + threadIdx.x;
  int stride = gridDim.x * blockDim.x;
  if (gid == 0) {
    counters[C_HASUN] = hasUn;
    counters[C_G] = K + hasUn;
    if (hasUn) groupCount[0] = un;
  }
  for (int j = gid; j < K; j += stride) {
    int myIdx = sIdx[j];
    int r = hasUn;
    for (int j2 = 0; j2 < K; ++j2)
      r += (sIdx[j2] < myIdx) ? 1 : 0;
    rankOfKept[j] = r;
    groupCount[r] = cntKept[j];
  }
}

__global__ void k_pointrank(int N, const int* __restrict__ keptPos,
                            const int* __restrict__ rankOfKept,
                            const int* __restrict__ assoInt,
                            int* __restrict__ pointRank, float* __restrict__ outAsso) {
  int i = blockIdx.x * blockDim.x + threadIdx.x;
  if (i >= N) return;
  int p = keptPos[i];
  pointRank[i] = (p < 0) ? 0 : rankOfKept[p];
  outAsso[i] = (float)assoInt[i];
}

// parallel exclusive prefix over groupCount[0..G) (single block, 256 threads)
__global__ void k_scan(const int* __restrict__ counters, const int* __restrict__ groupCount,
                       int* __restrict__ starts) {
  __shared__ int partial[256];
  int G = counters[C_G];
  int t = threadIdx.x;
  const int PER = (KMAX + 2 + 255) / 256;
  int sum = 0;
  for (int q = 0; q < PER; ++q) {
    int idx = t * PER + q;
    if (idx < G) sum += groupCount[idx];
  }
  partial[t] = sum;
  __syncthreads();
  if (t == 0) {
    int acc = 0;
    for (int i = 0; i < 256; ++i) { int v = partial[i]; partial[i] = acc; acc += v; }
  }
  __syncthreads();
  int acc = partial[t];
  for (int q = 0; q < PER; ++q) {
    int idx = t * PER + q;
    if (idx < G) { starts[idx] = acc; acc += groupCount[idx]; }
  }
}

__global__ void k_psrs(int N, const int* __restrict__ counters, const int* __restrict__ starts,
                       float* __restrict__ outPsrs) {
  int p = blockIdx.x * blockDim.x + threadIdx.x;
  if (p > N) return;
  int G = counters[C_G];
  outPsrs[p] = (p < G) ? (float)starts[p] : (float)N;
}

// ---- 3-pass stable counting-sort scatter (R4: verified, replaced O(G*N) scan) ----

// pass 1: per-chunk rank histogram (chunk c = points [c*SCHUNK, (c+1)*SCHUNK))
__global__ void __launch_bounds__(256) k_hist(
    int N, int C, const int* __restrict__ counters,
    const int* __restrict__ pointRank, int* __restrict__ chunkHist) {
  __shared__ int h[KMAX + 2];   // 16 KiB
  int G = counters[C_G];
  for (int g = threadIdx.x; g < G; g += 256) h[g] = 0;
  __syncthreads();
  int c = blockIdx.x;
  int i0 = c * SCHUNK;
  for (int q = 0; q < SCHUNK; q += 256) {
    int i = i0 + q + threadIdx.x;
    if (i < N) atomicAdd(&h[pointRank[i]], 1);
  }
  __syncthreads();
  for (int g = threadIdx.x; g < G; g += 256)
    chunkHist[(size_t)g * C + c] = h[g];
}

// pass 2: in-place exclusive scan over chunks per group, seeded with starts[g]
__global__ void k_chunkbase(int C, const int* __restrict__ counters,
                            const int* __restrict__ starts, int* __restrict__ chunkHist) {
  int g = blockIdx.x * blockDim.x + threadIdx.x;
  if (g >= counters[C_G]) return;
  int acc = starts[g];
  size_t base = (size_t)g * C;
  for (int c = 0; c < C; ++c) {
    int v = chunkHist[base + c];
    chunkHist[base + c] = acc;
    acc += v;
  }
}

// pass 3: scatter; stability = ascending batch order + ascending tid within batch
__global__ void __launch_bounds__(256) k_scatter2(
    int N, int C, const int* __restrict__ counters,
    const int* __restrict__ pointRank, const int* __restrict__ chunkBase,
    int* __restrict__ order, float* __restrict__ outSids,
    float* __restrict__ outBelongs) {
  __shared__ int baseL[KMAX + 2];   // 16 KiB running per-group write cursor
  __shared__ int ranks[256];
  int G = counters[C_G];
  int c = blockIdx.x;
  for (int g = threadIdx.x; g < G; g += 256)
    baseL[g] = chunkBase[(size_t)g * C + c];
  __syncthreads();
  int i0 = c * SCHUNK;
  int t = threadIdx.x;
  for (int q = 0; q < SCHUNK; q += 256) {
    int i = i0 + q + t;
    int r = -1;
    if (i < N) r = pointRank[i];
    ranks[t] = r;
    __syncthreads();
    if (i < N) {
      int cnt = 0;
      for (int j = 0; j < 256; ++j)          // uniform j -> LDS broadcast read
        cnt += (j < t && ranks[j] == r) ? 1 : 0;
      int pos = baseL[r] + cnt;
      order[pos] = i;
      outSids[pos] = (float)i;
      outBelongs[pos] = (float)r;
    }
    __syncthreads();
    if (i < N) atomicAdd(&baseL[r], 1);       // advance cursors for next batch
    __syncthreads();
  }
}

// flat grid-stride float4 row gather (F % 4 == 0 path)
__global__ void k_gather4(const float4* __restrict__ data4, const int* __restrict__ order,
                          int F4, int total4, float4* __restrict__ out4) {
  int stride = gridDim.x * blockDim.x;
  for (int idx = blockIdx.x * blockDim.x + threadIdx.x; idx < total4; idx += stride) {
    int row = idx / F4;
    int col = idx - row * F4;
    out4[idx] = data4[(size_t)order[row] * F4 + col];
  }
}

__global__ void k_gather(const float* __restrict__ data, const int* __restrict__ order,
                         int F, float* __restrict__ out) {
  int row = blockIdx.x;
  int src = order[row];
  for (int f = threadIdx.x; f < F; f += blockDim.x)
    out[(size_t)row * F + f] = data[(size_t)src * F + f];
}

extern "C" void kernel_launch(void* const* d_in, const int* in_sizes, int n_in,
                              void* d_out, int out_size, void* d_ws, size_t ws_size,
                              hipStream_t stream) {
  const float* data  = (const float*)d_in[0];
  const float* cc    = (const float*)d_in[1];
  const float* betas = (const float*)d_in[2];
  const int*   rs    = (const int*)d_in[3];
  int nrs = in_sizes[3];
  int N   = in_sizes[2];           // betas is (N,1)
  int F   = in_sizes[0] / N;       // 128
  int nseg = nrs - 1; if (nseg < 1) nseg = 1; if (nseg > NSEG_MAX) nseg = NSEG_MAX;
  int C   = (N + SCHUNK - 1) / SCHUNK;

  float* out = (float*)d_out;
  float* outSdata   = out;
  float* outPsrs    = outSdata + (size_t)N * F;
  float* outSids    = outPsrs + (N + 1);
  float* outAsso    = outSids + N;
  float* outBelongs = outAsso + N;

  char* p = (char*)d_ws;
  auto alloc = [&](size_t bytes) { void* r = (void*)p; p += (bytes + 255) & ~(size_t)255; return r; };
  int*    counters     = (int*)alloc(64 * 4);
  float4* ucand        = (float4*)alloc((size_t)N * 16);
  int*    uidx         = (int*)alloc((size_t)N * 4);
  int*    ubkt         = (int*)alloc((size_t)N * 4);
  float4* scand        = (float4*)alloc((size_t)N * 16);
  int*    sidx         = (int*)alloc((size_t)N * 4);
  int*    bucketCnt    = (int*)alloc(NBTOT * 4);
  int*    bucketStart  = (int*)alloc((NBTOT + 1) * 4);
  int*    bucketFill   = (int*)alloc(NBTOT * 4);
  float4* segKeptCand  = (float4*)alloc((size_t)NSEG_MAX * KSEG * 16);
  int*    segKeptIdx   = (int*)alloc((size_t)NSEG_MAX * KSEG * 4);
  int*    keptCntSeg   = (int*)alloc(NSEG_MAX * 4);
  int*    segKeptStart = (int*)alloc(NSEG_MAX * 4);
  int*    segKeptCnt   = (int*)alloc(NSEG_MAX * 4);
  float4* keptCand     = (float4*)alloc(KMAX * 16);
  int*    keptIdx      = (int*)alloc(KMAX * 4);
  int*    rankOfKept   = (int*)alloc(KMAX * 4);
  int*    cntKept      = (int*)alloc(KMAX * 4);
  int*    groupCount   = (int*)alloc((KMAX + 2) * 4);
  int*    starts       = (int*)alloc((KMAX + 2) * 4);
  int*    assoInt      = (int*)alloc((size_t)N * 4);
  int*    keptPos      = (int*)alloc((size_t)N * 4);
  int*    pointRank    = (int*)alloc((size_t)N * 4);
  int*    order        = (int*)alloc((size_t)N * 4);
  int*    chunkHist    = (int*)alloc((size_t)(KMAX + 2) * C * 4);

  int nb = (N + 255) / 256;

  k_init<<<(NBTOT + 255) / 256, 256, 0, stream>>>(counters, cntKept, groupCount,
                                                  bucketCnt, bucketFill);

  k_compact<<<nb, 256, 0, stream>>>(betas, cc, rs, nrs, N, ucand, uidx, ubkt,
                                    bucketCnt, &counters[C_U0]);

  k_bucketscan<<<1, 256, 0, stream>>>(bucketCnt, bucketStart);

  k_bucketscatter<<<nb, 256, 0, stream>>>(counters, ucand, uidx, ubkt,
                                          bucketStart, bucketFill, scand, sidx);

  k_bucketsort<<<NBTOT / 256, 256, 0, stream>>>(bucketCnt, bucketStart, scand, sidx);

  k_greedy<<<nseg, 256, 0, stream>>>(scand, sidx, bucketStart,
                                     segKeptCand, segKeptIdx, keptCntSeg);

  k_merge<<<1, 256, 0, stream>>>(nseg, segKeptCand, segKeptIdx, keptCntSeg,
                                 keptCand, keptIdx, segKeptStart, segKeptCnt, counters);

  k_assign<<<nb, 256, 0, stream>>>(cc, rs, nrs, N, keptCand, keptIdx,
                                   segKeptStart, segKeptCnt, counters, cntKept, counters,
                                   assoInt, keptPos);

  k_rank<<<32, 256, 0, stream>>>(keptIdx, counters, cntKept, rankOfKept, groupCount);

  k_pointrank<<<nb, 256, 0, stream>>>(N, keptPos, rankOfKept, assoInt, pointRank, outAsso);

  k_scan<<<1, 256, 0, stream>>>(counters, groupCount, starts);

  k_psrs<<<(N + 256) / 256, 256, 0, stream>>>(N, counters, starts, outPsrs);

  k_hist<<<C, 256, 0, stream>>>(N, C, counters, pointRank, chunkHist);

  k_chunkbase<<<(KMAX + 2 + 255) / 256, 256, 0, stream>>>(C, counters, starts, chunkHist);

  k_scatter2<<<C, 256, 0, stream>>>(N, C, counters, pointRank, chunkHist,
                                    order, outSids, outBelongs);

  if (F % 4 == 0) {
    int F4 = F / 4;
    int total4 = N * F4;
    k_gather4<<<2048, 256, 0, stream>>>((const float4*)data, order, F4, total4,
                                        (float4*)outSdata);
  } else {
    k_gather<<<N, 128, 0, stream>>>(data, order, F, outSdata);
  }
}